// Round 19
// baseline (448.456 us; speedup 1.0000x reference)
//
#include <hip/hip_runtime.h>
#include <stdint.h>

// NystromAttention MI355X — Round 19: bitwise-safe rebalance.
//  - Sweep split 4+1 (sweep sequence unchanged -> bitwise identical; moves
//    ~35us of SVD out of the fused2 window, which is ker3kv-bound at ~80us).
//  - kv_combine+mmat fused into one kernel (combine -> LDS -> mmat; identical
//    summation order; drops kvb roundtrip + one launch).
// Rest identical to R18 (passed, 429us, absmax 1.525879e-4).

constexpr int B_   = 2;
constexpr int N_   = 16384;
constexpr int C_   = 512;
constexpr int H_   = 8;
constexpr int HD_  = 64;
constexpr int LM_  = 64;
constexpr int SEG_ = 256;
constexpr int BH_  = 16;
constexpr int NCH_ = 16;
constexpr int NPART_ = 64;
constexpr int SW1_ = 4;   // sweeps in phase 1 (8-wave)
constexpr int SW2_ = 1;   // sweeps in phase 2 (4-wave); total 5 = R15..R18

#define RCOND_ (640.0 * 1.1920928955078125e-07)

typedef unsigned short ushort4_t __attribute__((ext_vector_type(4)));
typedef unsigned short ushort8_t __attribute__((ext_vector_type(8)));
typedef __bf16 bf16x8 __attribute__((ext_vector_type(8)));
typedef float f32x4 __attribute__((ext_vector_type(4)));

__device__ inline float bf2f(unsigned short u) {
  union { unsigned int i; float f; } x; x.i = ((unsigned int)u) << 16; return x.f;
}
__device__ inline unsigned short f2bf(float f) {
  union { float f; unsigned int i; } x; x.f = f;
  unsigned int lsb = (x.i >> 16) & 1;
  return (unsigned short)((x.i + 0x7fffu + lsb) >> 16);
}
__device__ inline bf16x8 ld_bf8(const unsigned short* p) { return *(const bf16x8*)p; }

__device__ __forceinline__ void gload_lds16(const unsigned short* gsrc, unsigned short* ldst) {
  __builtin_amdgcn_global_load_lds((const __attribute__((address_space(1))) void*)gsrc,
                                   (__attribute__((address_space(3))) void*)ldst, 16, 0, 0);
}

// ---------------------------------------------------------------------------
__global__ __launch_bounds__(256) void cvt_w4_kernel(const float* __restrict__ wq,
                                                     const float* __restrict__ wk,
                                                     const float* __restrict__ wv,
                                                     const float* __restrict__ wo,
                                                     unsigned short* __restrict__ dq,
                                                     unsigned short* __restrict__ dk,
                                                     unsigned short* __restrict__ dv,
                                                     unsigned short* __restrict__ dwo) {
  int which = blockIdx.y;
  const float* src = which == 0 ? wq : which == 1 ? wk : which == 2 ? wv : wo;
  unsigned short* dst = which == 0 ? dq : which == 1 ? dk : which == 2 ? dv : dwo;
  int i = blockIdx.x * 256 + threadIdx.x;
  const float* s = src + (size_t)i * 8;
  float4 x0 = *(const float4*)(s);
  float4 x1 = *(const float4*)(s + 4);
  ushort8_t u;
  u[0] = f2bf(x0.x); u[1] = f2bf(x0.y); u[2] = f2bf(x0.z); u[3] = f2bf(x0.w);
  u[4] = f2bf(x1.x); u[5] = f2bf(x1.y); u[6] = f2bf(x1.z); u[7] = f2bf(x1.w);
  *(ushort8_t*)(dst + (size_t)i * 8) = u;
}

// ---------------------------------------------------------------------------
// Segment means of x -> xbar; also emits xb = bf16(x).
__global__ __launch_bounds__(256) void seg_mean_kernel(const float* __restrict__ x,
                                                       float* __restrict__ xbar,
                                                       unsigned short* __restrict__ xb) {
  int bl = blockIdx.x;
  int b = bl / LM_, l = bl % LM_;
  int t = threadIdx.x;
  int c4 = t & 127;
  int rh = t >> 7;
  const size_t rowbase = (size_t)b * N_ + (size_t)l * SEG_;
  const float* xp = x + rowbase * C_;
  float4 s = make_float4(0.f, 0.f, 0.f, 0.f);
  for (int r = rh * 128; r < rh * 128 + 128; ++r) {
    float4 v = *(const float4*)(xp + (size_t)r * C_ + c4 * 4);
    s.x += v.x; s.y += v.y; s.z += v.z; s.w += v.w;
    ushort4_t u;
    u[0] = f2bf(v.x); u[1] = f2bf(v.y); u[2] = f2bf(v.z); u[3] = f2bf(v.w);
    *(ushort4_t*)(xb + (rowbase + r) * C_ + c4 * 4) = u;
  }
  __shared__ float red[2][512];
  *(float4*)&red[rh][c4 * 4] = s;
  __syncthreads();
  if (rh == 0) {
    float4 a = *(float4*)&red[0][c4 * 4];
    float4 c = *(float4*)&red[1][c4 * 4];
    const float invs = 1.0f / SEG_;
    float4 o;
    o.x = (a.x + c.x) * invs; o.y = (a.y + c.y) * invs;
    o.z = (a.z + c.z) * invs; o.w = (a.w + c.w) * invs;
    *(float4*)(xbar + (size_t)bl * C_ + c4 * 4) = o;
  }
}

// ---------------------------------------------------------------------------
// Merged landmark projections (f32 VALU GEMM, 128 rows) with bf16 epilogue.
__global__ __launch_bounds__(256) void land_gemm_kernel(const float* __restrict__ xbar,
                                                        const float* __restrict__ wq,
                                                        const float* __restrict__ bq,
                                                        const float* __restrict__ wk,
                                                        const float* __restrict__ bk,
                                                        float* __restrict__ qland,
                                                        float* __restrict__ kland,
                                                        unsigned short* __restrict__ qlbh,
                                                        unsigned short* __restrict__ qlbl,
                                                        unsigned short* __restrict__ klb) {
  __shared__ float As[32][68];
  __shared__ float Ws[32][68];
  int which = blockIdx.x >> 1;
  int row0 = (blockIdx.x & 1) * 64;
  int col0 = blockIdx.y * 64;
  const float* A = xbar;
  const float* W = which ? wk : wq;
  const float* bias = which ? bk : bq;
  float scale = which ? 1.0f : 0.125f;
  float* out = which ? kland : qland;
  int tid = threadIdx.x;
  int tm = tid >> 4, tn = tid & 15;
  float acc[4][4] = {};
  for (int k0 = 0; k0 < C_; k0 += 32) {
#pragma unroll
    for (int i = 0; i < 2; ++i) {
      int s = tid + i * 256;
      int r = s >> 3;
      int kg = (s & 7) << 2;
      float4 av = *(const float4*)(A + (size_t)(row0 + r) * C_ + k0 + kg);
      As[kg + 0][r] = av.x; As[kg + 1][r] = av.y;
      As[kg + 2][r] = av.z; As[kg + 3][r] = av.w;
      float4 wv = *(const float4*)(W + (size_t)(col0 + r) * C_ + k0 + kg);
      Ws[kg + 0][r] = wv.x; Ws[kg + 1][r] = wv.y;
      Ws[kg + 2][r] = wv.z; Ws[kg + 3][r] = wv.w;
    }
    __syncthreads();
#pragma unroll
    for (int kk = 0; kk < 32; ++kk) {
      float4 a = *(const float4*)&As[kk][tm * 4];
      float4 b = *(const float4*)&Ws[kk][tn * 4];
      float av[4] = {a.x, a.y, a.z, a.w};
      float bv[4] = {b.x, b.y, b.z, b.w};
#pragma unroll
      for (int i = 0; i < 4; ++i)
#pragma unroll
        for (int j = 0; j < 4; ++j) acc[i][j] += av[i] * bv[j];
    }
    __syncthreads();
  }
#pragma unroll
  for (int i = 0; i < 4; ++i) {
    int row = row0 + tm * 4 + i;
    int d0 = tn * 4;
    float o4[4];
#pragma unroll
    for (int j = 0; j < 4; ++j) o4[j] = (acc[i][j] + bias[col0 + d0 + j]) * scale;
    int b = row / LM_, n = row % LM_;
    int h = col0 >> 6;
    size_t idx = (((size_t)(b * H_ + h) * LM_) + n) * HD_ + d0;
    float4 o; o.x = o4[0]; o.y = o4[1]; o.z = o4[2]; o.w = o4[3];
    *(float4*)(out + idx) = o;
    if (which == 0) {
      ushort4_t uh, ul;
#pragma unroll
      for (int j = 0; j < 4; ++j) {
        unsigned short hbits = f2bf(o4[j]);
        uh[j] = hbits;
        ul[j] = f2bf(o4[j] - bf2f(hbits));
      }
      *(ushort4_t*)(qlbh + idx) = uh;
      *(ushort4_t*)(qlbl + idx) = ul;
    } else {
      ushort4_t uk;
#pragma unroll
      for (int j = 0; j < 4; ++j) uk[j] = f2bf(o4[j]);
      *(ushort4_t*)(klb + idx) = uk;
    }
  }
}

// ---------------------------------------------------------------------------
// DMA-staged bf16 MFMA GEMM body (ltid in 0..255; per-tile LDS Xs/Wl 8KB each).
__device__ __forceinline__ void dma_gemm_body(const unsigned short* __restrict__ A,
                                              const unsigned short* __restrict__ W,
                                              const float* __restrict__ bias,
                                              void* __restrict__ out,
                                              float scale, int omode,
                                              int row0, int col0,
                                              unsigned short* Xs, unsigned short* Wl,
                                              int tid) {
  int w = tid >> 6, lane = tid & 63;
  int wr = w >> 1, wc = w & 1;
  f32x4 acc[4][4] = {};

  for (int k0 = 0; k0 < C_; k0 += 32) {
    __syncthreads();
#pragma unroll
    for (int i = 0; i < 2; ++i) {
      const unsigned short* gx = A + (size_t)(row0 + w * 32 + i * 16 + (lane >> 2)) * C_ + k0 + (lane & 3) * 8;
      gload_lds16(gx, &Xs[(w * 32 + i * 16) * 32]);
      const unsigned short* gw = W + (size_t)(col0 + w * 32 + i * 16 + (lane >> 2)) * C_ + k0 + (lane & 3) * 8;
      gload_lds16(gw, &Wl[(w * 32 + i * 16) * 32]);
    }
    __syncthreads();
    bf16x8 af[4], bfr[4];
#pragma unroll
    for (int m = 0; m < 4; ++m)
      af[m] = *(bf16x8*)&Xs[(wr * 64 + m * 16 + (lane & 15)) * 32 + (lane >> 4) * 8];
#pragma unroll
    for (int n = 0; n < 4; ++n)
      bfr[n] = *(bf16x8*)&Wl[(wc * 64 + n * 16 + (lane & 15)) * 32 + (lane >> 4) * 8];
#pragma unroll
    for (int m = 0; m < 4; ++m)
#pragma unroll
      for (int n = 0; n < 4; ++n)
        acc[m][n] = __builtin_amdgcn_mfma_f32_16x16x32_bf16(af[m], bfr[n], acc[m][n], 0, 0, 0);
  }

#pragma unroll
  for (int m = 0; m < 4; ++m) {
    int rbase = row0 + wr * 64 + m * 16 + (lane >> 4) * 4;
#pragma unroll
    for (int n = 0; n < 4; ++n) {
      int c = col0 + wc * 64 + n * 16 + (lane & 15);
      float bc = bias[c];
      if (omode == 0) {
#pragma unroll
        for (int rg = 0; rg < 4; ++rg)
          ((float*)out)[(size_t)(rbase + rg) * C_ + c] = acc[m][n][rg] + bc;
      } else if (omode == 2) {
        int b = rbase >> 14, nn = rbase & 16383;
        int h = c >> 6, d = c & 63;
        ushort4_t u;
#pragma unroll
        for (int rg = 0; rg < 4; ++rg) u[rg] = f2bf((acc[m][n][rg] + bc) * scale);
        *(ushort4_t*)((unsigned short*)out + ((size_t)(b * H_ + h) * HD_ + d) * N_ + nn) = u;
      } else {
#pragma unroll
        for (int rg = 0; rg < 4; ++rg) {
          float val = (acc[m][n][rg] + bc) * scale;
          int r = rbase + rg;
          int b = r >> 14, nn = r & 16383, h = c >> 6, d = c & 63;
          ((unsigned short*)out)[(((size_t)(b * H_ + h) * N_) + nn) * HD_ + d] = f2bf(val);
        }
      }
    }
  }
}

// ---------------------------------------------------------------------------
// SVD sweep loop, NW waves (NW*64 threads), RP=64/NW rows per thread.
template <int NW>
__device__ __forceinline__ void svd_sweeps(float* a, float* v, char* smemraw,
                                           int w, int lane, int nsweeps) {
  constexpr int RP = 64 / NW;
  float (*Ac)[68] = (float(*)[68])(smemraw);
  float (*Vc)[68] = (float(*)[68])(smemraw + 17408);
  float (*pg)[NW][64] = (float(*)[NW][64])(smemraw + 34816);
  float (*pa)[64] = (float(*)[64])(smemraw + 34816 + 2 * NW * 64 * 4);
  const int r0 = w * RP;
#pragma unroll
  for (int c = 0; c < RP; c += 4) {
    *(float4*)&Ac[lane][r0 + c] = make_float4(a[c], a[c + 1], a[c + 2], a[c + 3]);
    *(float4*)&Vc[lane][r0 + c] = make_float4(v[c], v[c + 1], v[c + 2], v[c + 3]);
  }

  for (int sweep = 0; sweep < nsweeps; ++sweep) {
    float p0 = 0.f, p1 = 0.f;
#pragma unroll
    for (int k = 0; k < RP; k += 2) { p0 = fmaf(a[k], a[k], p0); p1 = fmaf(a[k + 1], a[k + 1], p1); }
    pa[w][lane] = p0 + p1;
    __syncthreads();
    float alpha;
    if constexpr (NW == 4)
      alpha = (pa[0][lane] + pa[1][lane]) + (pa[2][lane] + pa[3][lane]);
    else
      alpha = ((pa[0][lane] + pa[1][lane]) + (pa[2][lane] + pa[3][lane])) +
              ((pa[4][lane] + pa[5][lane]) + (pa[6][lane] + pa[7][lane]));
    for (int mask = 1; mask < 64; ++mask) {
      int buf = mask & 1;
      int partner = lane ^ mask;
      bool lower = lane < partner;
      float beta = __shfl_xor(alpha, mask);
      float o[RP];
#pragma unroll
      for (int c = 0; c < RP; c += 4) {
        float4 t4 = *(float4*)&Ac[partner][r0 + c];
        o[c] = t4.x; o[c + 1] = t4.y; o[c + 2] = t4.z; o[c + 3] = t4.w;
      }
      float g0 = 0.f, g1 = 0.f;
#pragma unroll
      for (int k = 0; k < RP; k += 2) { g0 = fmaf(a[k], o[k], g0); g1 = fmaf(a[k + 1], o[k + 1], g1); }
      pg[buf][w][lane] = g0 + g1;
      __syncthreads();
      float gamma;
      if constexpr (NW == 4)
        gamma = (pg[buf][0][lane] + pg[buf][1][lane]) + (pg[buf][2][lane] + pg[buf][3][lane]);
      else
        gamma = ((pg[buf][0][lane] + pg[buf][1][lane]) + (pg[buf][2][lane] + pg[buf][3][lane])) +
                ((pg[buf][4][lane] + pg[buf][5][lane]) + (pg[buf][6][lane] + pg[buf][7][lane]));
      bool need = (gamma * gamma > 1e-12f * alpha * beta);
      if (__any(need)) {
        float ov[RP];
#pragma unroll
        for (int c = 0; c < RP; c += 4) {
          float4 t4 = *(float4*)&Vc[partner][r0 + c];
          ov[c] = t4.x; ov[c + 1] = t4.y; ov[c + 2] = t4.z; ov[c + 3] = t4.w;
        }
        float ap = lower ? alpha : beta;
        float aq = lower ? beta : alpha;
        float c = 1.f, s = 0.f;
        if (need) {
          float tau = (aq - ap) / (2.f * gamma);
          float t = copysignf(1.f, tau) / (fabsf(tau) + sqrtf(fmaf(tau, tau, 1.f)));
          c = rsqrtf(fmaf(t, t, 1.f));
          s = t * c;
        }
        float sm = lower ? -s : s;
#pragma unroll
        for (int k = 0; k < RP; ++k) a[k] = fmaf(sm, o[k], c * a[k]);
#pragma unroll
        for (int k = 0; k < RP; ++k) v[k] = fmaf(sm, ov[k], c * v[k]);
        float twocsg = 2.f * c * s * gamma;
        alpha = fmaf(c * c, alpha, fmaf(s * s, beta, lower ? -twocsg : twocsg));
#pragma unroll
        for (int cc = 0; cc < RP; cc += 4) {
          *(float4*)&Ac[lane][r0 + cc] = make_float4(a[cc], a[cc + 1], a[cc + 2], a[cc + 3]);
          *(float4*)&Vc[lane][r0 + cc] = make_float4(v[cc], v[cc + 1], v[cc + 2], v[cc + 3]);
        }
      }
    }
  }
}

// Phase 1 (8-wave, 512 threads): ker2 in-LDS, SW1_ sweeps, save state.
__device__ void svd_phase1(const float* __restrict__ qland, const float* __restrict__ kland,
                           float* __restrict__ asave, float* __restrict__ vsave,
                           int bh, char* smemraw, int tid) {
  __builtin_amdgcn_s_setprio(3);
  float (*qlS)[65] = (float(*)[65])(smemraw);
  float (*klS)[65] = (float(*)[65])(smemraw + 16640);
  for (int i = 0; i < 2; ++i) {
    int s = tid + i * 512;
    int r = s >> 4, d4 = (s & 15) << 2;
    *(float4*)&qlS[r][d4] = *(const float4*)(qland + ((size_t)bh * 64 + r) * 64 + d4);
    *(float4*)&klS[r][d4] = *(const float4*)(kland + ((size_t)bh * 64 + r) * 64 + d4);
  }
  __syncthreads();
  int w = tid >> 6, lane = tid & 63;
  float a[8], v[8];
#pragma unroll
  for (int k = 0; k < 8; ++k) {
    int row = w * 8 + k;
    float acc = 0.f;
#pragma unroll
    for (int d4 = 0; d4 < 64; d4 += 4) {
      float4 qv = *(float4*)&qlS[row][d4];
      float4 kv = *(float4*)&klS[lane][d4];
      acc += qv.x * kv.x + qv.y * kv.y + qv.z * kv.z + qv.w * kv.w;
    }
    float e = expf(acc);
    float rs = e;
#pragma unroll
    for (int m = 1; m < 64; m <<= 1) rs += __shfl_xor(rs, m);
    a[k] = e * (1.f / rs);
  }
#pragma unroll
  for (int k = 0; k < 8; ++k) v[k] = (w * 8 + k == lane) ? 1.f : 0.f;
  __syncthreads();   // qlS/klS dead; Ac/Vc overlay safe
  svd_sweeps<8>(a, v, smemraw, w, lane, SW1_);
#pragma unroll
  for (int k = 0; k < 8; ++k) {
    asave[((size_t)bh * 64 + w * 8 + k) * 64 + lane] = a[k];
    vsave[((size_t)bh * 64 + w * 8 + k) * 64 + lane] = v[k];
  }
  __builtin_amdgcn_s_setprio(0);
}

// Phase 2 (4-wave, 256 threads): load state, SW2_ sweeps, sigma/cutoff + pinv.
__device__ void svd_phase2(const float* __restrict__ asave, const float* __restrict__ vsave,
                           float* __restrict__ pinv, int bh, char* smemraw, int tid) {
  __builtin_amdgcn_s_setprio(3);
  double (*ps2)[64]  = (double(*)[64])(smemraw + 37888);
  float (*vsL)[65]   = (float(*)[65])(smemraw);
  float (*wasL)[65]  = (float(*)[65])(smemraw + 16640);
  int w = tid >> 6, lane = tid & 63;
  float a[16], v[16];
#pragma unroll
  for (int k = 0; k < 16; ++k) {
    a[k] = asave[((size_t)bh * 64 + w * 16 + k) * 64 + lane];
    v[k] = vsave[((size_t)bh * 64 + w * 16 + k) * 64 + lane];
  }
  svd_sweeps<4>(a, v, smemraw, w, lane, SW2_);

  double psig = 0.0;
#pragma unroll
  for (int k = 0; k < 16; ++k) psig += (double)a[k] * (double)a[k];
  ps2[w][lane] = psig;
  __syncthreads();
  double sig2 = (ps2[0][lane] + ps2[1][lane]) + (ps2[2][lane] + ps2[3][lane]);
  double smax = sig2;
#pragma unroll
  for (int m = 1; m < 64; m <<= 1) smax = fmax(smax, __shfl_xor(smax, m));
  double cutoff2 = smax * (RCOND_ * RCOND_);
  float wgt = (sig2 > cutoff2) ? (float)(1.0 / sig2) : 0.f;

#pragma unroll
  for (int k = 0; k < 16; ++k) {
    vsL[lane][w * 16 + k] = v[k];
    wasL[lane][w * 16 + k] = wgt * a[k];
  }
  __syncthreads();
  int i = tid >> 2;
  int j0 = (tid & 3) * 16;
  float acc[16] = {};
  for (int r = 0; r < 64; ++r) {
    float vv = vsL[r][i];
#pragma unroll
    for (int jj = 0; jj < 16; ++jj) acc[jj] = fmaf(vv, wasL[r][j0 + jj], acc[jj]);
  }
#pragma unroll
  for (int jj = 0; jj < 16; jj += 4) {
    float4 ovv = make_float4(acc[jj], acc[jj + 1], acc[jj + 2], acc[jj + 3]);
    *(float4*)(pinv + ((size_t)bh * 64 + i) * 64 + j0 + jj) = ovv;
  }
  __builtin_amdgcn_s_setprio(0);
}

// ---------------------------------------------------------------------------
// Fused 1 (512 threads): blocks 0..15 = SVD phase 1 (8-wave);
// blocks 16..1551 = DMA projections, two 128^2 tiles per block.
__global__ __launch_bounds__(512) void fused1_kernel(
    const unsigned short* __restrict__ xb,
    const unsigned short* __restrict__ wqb, const float* __restrict__ bq,
    const unsigned short* __restrict__ wkb, const float* __restrict__ bk,
    const unsigned short* __restrict__ wvb, const float* __restrict__ bv,
    unsigned short* __restrict__ q4, unsigned short* __restrict__ k4,
    unsigned short* __restrict__ vt,
    const float* __restrict__ qland, const float* __restrict__ kland,
    float* __restrict__ asave, float* __restrict__ vsave) {
  __shared__ __align__(16) char smem[40960];
  int tid = threadIdx.x;
  int blk = blockIdx.x;
  if (blk < 16) { svd_phase1(qland, kland, asave, vsave, blk, smem, tid); return; }
  int g = blk - 16;
  int which = g >> 9;          // 512 blocks per projection
  int subpair = g & 511;
  int half = tid >> 8;
  int ltid = tid & 255;
  int sub = subpair * 2 + half;
  int row0 = (sub >> 2) * 128;
  int col0 = (sub & 3) * 128;
  unsigned short* Xs = (unsigned short*)(smem + half * 16384);
  unsigned short* Wl = Xs + 128 * 32;
  if (which == 0)
    dma_gemm_body(xb, wqb, bq, q4, 0.125f, 1, row0, col0, Xs, Wl, ltid);
  else if (which == 1)
    dma_gemm_body(xb, wkb, bk, k4, 1.0f, 1, row0, col0, Xs, Wl, ltid);
  else
    dma_gemm_body(xb, wvb, bv, vt, 1.0f, 2, row0, col0, Xs, Wl, ltid);
}

// ---------------------------------------------------------------------------
// ker3+kv body (deviation form, MFMA) — unchanged math.
__device__ void ker3kv_body(const unsigned short* __restrict__ qlh,
                            const unsigned short* __restrict__ qll,
                            const unsigned short* __restrict__ k4,
                            const unsigned short* __restrict__ vt,
                            float* __restrict__ pacc,
                            float* __restrict__ pacc0,
                            float* __restrict__ ps,
                            int bh, int ch, char* smemraw, int tid) {
  int w = tid >> 6, lane = tid & 63;
  int part = ch * 4 + w;
  int lrow = lane & 15, lgrp = lane >> 4;
  unsigned short* myP = (unsigned short*)smemraw + w * 64 * 72;

  bf16x8 qah[4][2], qal[4][2];
#pragma unroll
  for (int mf = 0; mf < 4; ++mf)
#pragma unroll
    for (int ks = 0; ks < 2; ++ks) {
      size_t off = ((size_t)bh * 64 + mf * 16 + lrow) * 64 + ks * 32 + lgrp * 8;
      qah[mf][ks] = ld_bf8(qlh + off);
      qal[mf][ks] = ld_bf8(qll + off);
    }
  bf16x8 onesf;
#pragma unroll
  for (int j = 0; j < 8; ++j) onesf[j] = (__bf16)1.0f;

  f32x4 kvacc[4][4] = {};
  f32x4 oneacc[4] = {};
  f32x4 ssum[4] = {};

  for (int sub = 0; sub < 4; ++sub) {
    int n0 = ch * 1024 + w * 256 + sub * 64;
    f32x4 sacc[4][4] = {};
#pragma unroll
    for (int ks = 0; ks < 2; ++ks) {
#pragma unroll
      for (int nf = 0; nf < 4; ++nf) {
        bf16x8 kb = ld_bf8(k4 + ((size_t)bh * N_ + n0 + nf * 16 + lrow) * 64 + ks * 32 + lgrp * 8);
#pragma unroll
        for (int mf = 0; mf < 4; ++mf) {
          sacc[mf][nf] = __builtin_amdgcn_mfma_f32_16x16x32_bf16(qah[mf][ks], kb, sacc[mf][nf], 0, 0, 0);
          sacc[mf][nf] = __builtin_amdgcn_mfma_f32_16x16x32_bf16(qal[mf][ks], kb, sacc[mf][nf], 0, 0, 0);
        }
      }
    }
#pragma unroll
    for (int mf = 0; mf < 4; ++mf) {
#pragma unroll
      for (int nf = 0; nf < 4; ++nf) {
#pragma unroll
        for (int r = 0; r < 4; ++r) {
          float pd = expf(sacc[mf][nf][r]) - 1.0f;
          ssum[mf][r] += pd;
          myP[(mf * 16 + lgrp * 4 + r) * 72 + nf * 16 + lrow] = f2bf(pd);
        }
      }
    }
#pragma unroll
    for (int ks = 0; ks < 2; ++ks) {
      bf16x8 pa[4];
#pragma unroll
      for (int mf = 0; mf < 4; ++mf)
        pa[mf] = ld_bf8(myP + (mf * 16 + lrow) * 72 + ks * 32 + lgrp * 8);
#pragma unroll
      for (int nf = 0; nf < 4; ++nf) {
        bf16x8 vb = ld_bf8(vt + ((size_t)bh * 64 + nf * 16 + lrow) * N_ + n0 + ks * 32 + lgrp * 8);
#pragma unroll
        for (int mf = 0; mf < 4; ++mf)
          kvacc[mf][nf] = __builtin_amdgcn_mfma_f32_16x16x32_bf16(pa[mf], vb, kvacc[mf][nf], 0, 0, 0);
        oneacc[nf] = __builtin_amdgcn_mfma_f32_16x16x32_bf16(onesf, vb, oneacc[nf], 0, 0, 0);
      }
    }
  }
#pragma unroll
  for (int mf = 0; mf < 4; ++mf)
#pragma unroll
    for (int m = 1; m < 16; m <<= 1)
#pragma unroll
      for (int r = 0; r < 4; ++r) ssum[mf][r] += __shfl_xor(ssum[mf][r], m);

  size_t pb = (((size_t)bh * NPART_ + part) * 64) * 64;
#pragma unroll
  for (int mf = 0; mf < 4; ++mf)
#pragma unroll
    for (int nf = 0; nf < 4; ++nf)
#pragma unroll
      for (int r = 0; r < 4; ++r)
        pacc[pb + (size_t)(mf * 16 + lgrp * 4 + r) * 64 + nf * 16 + lrow] = kvacc[mf][nf][r];
  if (lrow == 0) {
#pragma unroll
    for (int mf = 0; mf < 4; ++mf)
#pragma unroll
      for (int r = 0; r < 4; ++r)
        ps[((size_t)bh * NPART_ + part) * 64 + mf * 16 + lgrp * 4 + r] = ssum[mf][r];
  }
  if (lgrp == 0) {
#pragma unroll
    for (int nf = 0; nf < 4; ++nf)
      pacc0[((size_t)bh * NPART_ + part) * 64 + nf * 16 + lrow] = oneacc[nf][0];
  }
}

// Fused 2: blocks 0..15 = SVD phase 2 (+pinv); 16..271 = ker3kv.
__global__ __launch_bounds__(256, 1) void fused2_kernel(
    const unsigned short* __restrict__ qlh,
    const unsigned short* __restrict__ qll,
    const unsigned short* __restrict__ k4,
    const unsigned short* __restrict__ vt,
    float* __restrict__ pacc, float* __restrict__ pacc0, float* __restrict__ ps,
    const float* __restrict__ asave, const float* __restrict__ vsave,
    float* __restrict__ pinv) {
  __shared__ __align__(16) char smem[39936];
  int tid = threadIdx.x;
  int blk = blockIdx.x;
  if (blk < 16) { svd_phase2(asave, vsave, pinv, blk, smem, tid); return; }
  int g = blk - 16;
  int bh = g >> 4, ch = g & 15;
  ker3kv_body(qlh, qll, k4, vt, pacc, pacc0, ps, bh, ch, smem, tid);
}

// ---------------------------------------------------------------------------
// Fused combine+mmat: per bh, combine partials into kvs (LDS) with the exact
// original summation order, then mmat (pinv@kv fp64 -> mt hi/lo + msum).
__global__ __launch_bounds__(256) void cm_kernel(const float* __restrict__ pacc,
                                                 const float* __restrict__ pacc0,
                                                 const float* __restrict__ ps,
                                                 const float* __restrict__ pinv,
                                                 unsigned short* __restrict__ mtbh,
                                                 unsigned short* __restrict__ mtbl,
                                                 float* __restrict__ msum) {
  int bh = blockIdx.x;
  int tid = threadIdx.x;
  __shared__ float kvs[64][68];
  __shared__ double pcsd[64];
  // combine phase (identical math/order to old kv_combine, 4 groups)
  for (int g = 0; g < 4; ++g) {
    int lm = g * 16 + (tid >> 4);
    int d4 = (tid & 15) * 4;
    float s = 16384.f;
    for (int part = 0; part < NPART_; ++part) s += ps[((size_t)bh * NPART_ + part) * 64 + lm];
    float4 a = make_float4(0.f, 0.f, 0.f, 0.f);
    for (int part = 0; part < NPART_; ++part) {
      float4 c0 = *(const float4*)&pacc0[((size_t)bh * NPART_ + part) * 64 + d4];
      float4 v = *(const float4*)&pacc[(((size_t)bh * NPART_ + part) * 64 + lm) * 64 + d4];
      a.x += c0.x + v.x; a.y += c0.y + v.y; a.z += c0.z + v.z; a.w += c0.w + v.w;
    }
    float inv = 1.f / s;
    kvs[lm][d4 + 0] = a.x * inv; kvs[lm][d4 + 1] = a.y * inv;
    kvs[lm][d4 + 2] = a.z * inv; kvs[lm][d4 + 3] = a.w * inv;
  }
  if (tid < 64) {
    double s = 0.0;
    for (int l = 0; l < 64; ++l) s += (double)pinv[((size_t)bh * 64 + l) * 64 + tid];
    pcsd[tid] = s;
  }
  __syncthreads();
  // mmat phase (identical to old mmat, kvs already in LDS)
  int l = tid >> 2, t = tid & 3;
  double o[16] = {};
  for (int j = 0; j < 64; ++j) {
    double pv = (double)pinv[((size_t)bh * 64 + l) * 64 + j];
#pragma unroll
    for (int i = 0; i < 16; ++i) o[i] += pv * (double)kvs[j][t * 16 + i];
  }
#pragma unroll
  for (int i = 0; i < 16; ++i) {
    float f = (float)o[i];
    unsigned short hi = f2bf(f);
    float lo = f - bf2f(hi);
    int d = t * 16 + i;
    mtbh[((size_t)bh * 64 + d) * 64 + l] = hi;
    mtbl[((size_t)bh * 64 + d) * 64 + l] = f2bf(lo);
  }
  if (tid < 64) {
    double m = 0.0;
    for (int j = 0; j < 64; ++j) m += pcsd[j] * (double)kvs[j][tid];
    msum[(size_t)bh * 64 + tid] = (float)(m * (1.0 / 64.0));
  }
}

// ---------------------------------------------------------------------------
__global__ __launch_bounds__(256, 1) void ker1out_mfma_kernel(
    const unsigned short* __restrict__ q4,
    const unsigned short* __restrict__ klb,
    const unsigned short* __restrict__ mtbh,
    const unsigned short* __restrict__ mtbl,
    const float* __restrict__ msum,
    unsigned short* __restrict__ outh) {
  int bh = blockIdx.y, tile = blockIdx.x;
  int b = bh >> 3, h = bh & 7;
  int tid = threadIdx.x, w = tid >> 6, lane = tid & 63;
  int lrow = lane & 15, lgrp = lane >> 4;
  int tok0 = tile * 256 + w * 64;
  __shared__ __align__(16) unsigned short Pl[4][64 * 72];
  unsigned short* myP = &Pl[w][0];

  f32x4 sacc[4][4] = {};
#pragma unroll
  for (int ks = 0; ks < 2; ++ks) {
    bf16x8 kb[4];
#pragma unroll
    for (int nf = 0; nf < 4; ++nf)
      kb[nf] = ld_bf8(klb + ((size_t)bh * 64 + nf * 16 + lrow) * 64 + ks * 32 + lgrp * 8);
#pragma unroll
    for (int mf = 0; mf < 4; ++mf) {
      bf16x8 qa = ld_bf8(q4 + ((size_t)bh * N_ + tok0 + mf * 16 + lrow) * 64 + ks * 32 + lgrp * 8);
#pragma unroll
      for (int nf = 0; nf < 4; ++nf)
        sacc[mf][nf] = __builtin_amdgcn_mfma_f32_16x16x32_bf16(qa, kb[nf], sacc[mf][nf], 0, 0, 0);
    }
  }
  f32x4 ssum[4] = {};
#pragma unroll
  for (int mf = 0; mf < 4; ++mf)
#pragma unroll
    for (int nf = 0; nf < 4; ++nf)
#pragma unroll
      for (int r = 0; r < 4; ++r) {
        sacc[mf][nf][r] = expf(sacc[mf][nf][r]);
        ssum[mf][r] += sacc[mf][nf][r];
      }
#pragma unroll
  for (int mf = 0; mf < 4; ++mf)
#pragma unroll
    for (int m = 1; m < 16; m <<= 1)
#pragma unroll
      for (int r = 0; r < 4; ++r) ssum[mf][r] += __shfl_xor(ssum[mf][r], m);
#pragma unroll
  for (int mf = 0; mf < 4; ++mf) {
    f32x4 inv;
#pragma unroll
    for (int r = 0; r < 4; ++r) inv[r] = 1.f / ssum[mf][r];
#pragma unroll
    for (int nf = 0; nf < 4; ++nf)
#pragma unroll
      for (int r = 0; r < 4; ++r) {
        float pdev = fmaf(sacc[mf][nf][r], inv[r], -0.015625f);
        myP[(mf * 16 + lgrp * 4 + r) * 72 + nf * 16 + lrow] = f2bf(pdev);
      }
  }

  f32x4 oacc[4][4] = {};
#pragma unroll
  for (int ks = 0; ks < 2; ++ks) {
    bf16x8 pa[4];
#pragma unroll
    for (int mf = 0; mf < 4; ++mf)
      pa[mf] = ld_bf8(myP + (mf * 16 + lrow) * 72 + ks * 32 + lgrp * 8);
#pragma unroll
    for (int nf = 0; nf < 4; ++nf) {
      bf16x8 mh = ld_bf8(mtbh + ((size_t)bh * 64 + nf * 16 + lrow) * 64 + ks * 32 + lgrp * 8);
      bf16x8 ml = ld_bf8(mtbl + ((size_t)bh * 64 + nf * 16 + lrow) * 64 + ks * 32 + lgrp * 8);
#pragma unroll
      for (int mf = 0; mf < 4; ++mf) {
        oacc[mf][nf] = __builtin_amdgcn_mfma_f32_16x16x32_bf16(pa[mf], mh, oacc[mf][nf], 0, 0, 0);
        oacc[mf][nf] = __builtin_amdgcn_mfma_f32_16x16x32_bf16(pa[mf], ml, oacc[mf][nf], 0, 0, 0);
      }
    }
  }
#pragma unroll
  for (int nf = 0; nf < 4; ++nf) {
    float ms = msum[(size_t)bh * 64 + nf * 16 + lrow];
#pragma unroll
    for (int mf = 0; mf < 4; ++mf)
#pragma unroll
      for (int r = 0; r < 4; ++r) {
        int tok = tok0 + mf * 16 + lgrp * 4 + r;
        int d = nf * 16 + lrow;
        outh[((size_t)b * N_ + tok) * C_ + h * HD_ + d] = f2bf(oacc[mf][nf][r] + ms);
      }
  }
}

// ---------------------------------------------------------------------------
// Final projection (serial tail): outh(bf16) @ wob^T(bf16) + bo -> f32 out.
__global__ __launch_bounds__(256) void oproj_kernel(const unsigned short* __restrict__ outh,
                                                    const unsigned short* __restrict__ wob,
                                                    const float* __restrict__ bo,
                                                    float* __restrict__ out) {
  __shared__ __align__(16) unsigned short Xs[128 * 32];
  __shared__ __align__(16) unsigned short Wl[128 * 32];
  dma_gemm_body(outh, wob, bo, out, 1.0f, 0, blockIdx.x * 128, blockIdx.y * 128,
                Xs, Wl, threadIdx.x);
}

// ---------------------------------------------------------------------------
extern "C" void kernel_launch(void* const* d_in, const int* in_sizes, int n_in,
                              void* d_out, int out_size, void* d_ws, size_t ws_size,
                              hipStream_t stream) {
  const float* x  = (const float*)d_in[0];
  const float* wq = (const float*)d_in[1];
  const float* bq = (const float*)d_in[2];
  const float* wk = (const float*)d_in[3];
  const float* bk = (const float*)d_in[4];
  const float* wv = (const float*)d_in[5];
  const float* bv = (const float*)d_in[6];
  const float* wo = (const float*)d_in[7];
  const float* bo = (const float*)d_in[8];
  float* out = (float*)d_out;

  char* base = (char*)d_ws;
  const size_t QKV = (size_t)BH_ * N_ * HD_;
  unsigned short* q4 = (unsigned short*)base;                 // 32MB
  unsigned short* k4 = (unsigned short*)(base + QKV * 2);     // 32MB
  unsigned short* vt = (unsigned short*)(base + QKV * 4);     // 32MB
  unsigned short* outh = (unsigned short*)(base + QKV * 2);   // alias k4 (dead after ker3kv)
  char* sp = base + QKV * 6;
  float* pacc  = (float*)sp; sp += (size_t)BH_ * NPART_ * 64 * 64 * 4;  // 16.78MB
  float* pacc0 = (float*)sp; sp += (size_t)BH_ * NPART_ * 64 * 4;
  float* ps    = (float*)sp; sp += (size_t)BH_ * NPART_ * 64 * 4;
  float* xbar  = (float*)sp; sp += (size_t)B_ * LM_ * C_ * 4;
  float* qland = (float*)sp; sp += (size_t)BH_ * LM_ * HD_ * 4;
  float* kland = (float*)sp; sp += (size_t)BH_ * LM_ * HD_ * 4;
  unsigned short* qlbh = (unsigned short*)sp; sp += (size_t)BH_ * LM_ * HD_ * 2;
  unsigned short* qlbl = (unsigned short*)sp; sp += (size_t)BH_ * LM_ * HD_ * 2;
  unsigned short* klb  = (unsigned short*)sp; sp += (size_t)BH_ * LM_ * HD_ * 2;
  float* pinv  = (float*)sp; sp += (size_t)BH_ * LM_ * LM_ * 4;
  unsigned short* mtbh = (unsigned short*)sp; sp += (size_t)BH_ * LM_ * HD_ * 2;
  unsigned short* mtbl = (unsigned short*)sp; sp += (size_t)BH_ * LM_ * HD_ * 2;
  float* msum  = (float*)sp; sp += (size_t)BH_ * HD_ * 4;
  float* asave = (float*)sp; sp += (size_t)BH_ * LM_ * LM_ * 4;   // 256KB
  float* vsave = (float*)sp; sp += (size_t)BH_ * LM_ * LM_ * 4;   // 256KB
  unsigned short* wob = (unsigned short*)sp; sp += (size_t)C_ * C_ * 2;  // 512KB
  unsigned short* wqb = (unsigned short*)sp; sp += (size_t)C_ * C_ * 2;  // 512KB
  unsigned short* wkb = (unsigned short*)sp; sp += (size_t)C_ * C_ * 2;  // 512KB
  unsigned short* wvb = (unsigned short*)sp; sp += (size_t)C_ * C_ * 2;  // 512KB

  // xb (bf16 x, 32MB) lives in d_out's first half (dead until oproj).
  unsigned short* xb = (unsigned short*)d_out;

  const int W8 = (C_ * C_) / 8;

  dim3 gc(W8 / 256, 4);
  cvt_w4_kernel<<<gc, 256, 0, stream>>>(wq, wk, wv, wo, wqb, wkb, wvb, wob);

  seg_mean_kernel<<<B_ * LM_, 256, 0, stream>>>(x, xbar, xb);
  dim3 gl(4, 8);
  land_gemm_kernel<<<gl, 256, 0, stream>>>(xbar, wq, bq, wk, bk,
                                           qland, kland, qlbh, qlbl, klb);

  // fused 1: SVD phase 1 (8-wave, 4 sweeps) + DMA projections (2 tiles/blk)
  fused1_kernel<<<16 + 3 * 512, 512, 0, stream>>>(
      xb, wqb, bq, wkb, bk, wvb, bv, q4, k4, vt, qland, kland, asave, vsave);

  // fused 2: SVD phase 2 (1 sweep + pinv) + ker3kv (256 blocks)
  fused2_kernel<<<16 + NCH_ * BH_, 256, 0, stream>>>(
      qlbh, qlbl, k4, vt, pacc, pacc0, ps, asave, vsave, pinv);

  // combine + M (fused)
  cm_kernel<<<BH_, 256, 0, stream>>>(pacc, pacc0, ps, pinv, mtbh, mtbl, msum);

  dim3 g9(N_ / 256, BH_);
  ker1out_mfma_kernel<<<g9, 256, 0, stream>>>(q4, klb, mtbh, mtbl, msum, outh);

  dim3 g10(B_ * N_ / 128, C_ / 128);
  oproj_kernel<<<g10, 256, 0, stream>>>(outh, wob, bo, out);
}

// Round 20
// 392.249 us; speedup vs baseline: 1.1433x; 1.1433x over previous
//
#include <hip/hip_runtime.h>
#include <stdint.h>

// NystromAttention MI355X — Round 20: revert sweep split to 3+2 (R19's 4+1
// made fused1 SVD-bound, +19us); keep cm fusion; fused2 -> 512 threads
// (8-wave SVD phase 2 + two ker3kv chunks/block); seg_mean -> 512 threads.

constexpr int B_   = 2;
constexpr int N_   = 16384;
constexpr int C_   = 512;
constexpr int H_   = 8;
constexpr int HD_  = 64;
constexpr int LM_  = 64;
constexpr int SEG_ = 256;
constexpr int BH_  = 16;
constexpr int NCH_ = 16;
constexpr int NPART_ = 64;
constexpr int SW1_ = 3;   // sweeps in phase 1 (8-wave)
constexpr int SW2_ = 2;   // sweeps in phase 2 (8-wave); total 5

#define RCOND_ (640.0 * 1.1920928955078125e-07)

typedef unsigned short ushort4_t __attribute__((ext_vector_type(4)));
typedef unsigned short ushort8_t __attribute__((ext_vector_type(8)));
typedef __bf16 bf16x8 __attribute__((ext_vector_type(8)));
typedef float f32x4 __attribute__((ext_vector_type(4)));

__device__ inline float bf2f(unsigned short u) {
  union { unsigned int i; float f; } x; x.i = ((unsigned int)u) << 16; return x.f;
}
__device__ inline unsigned short f2bf(float f) {
  union { float f; unsigned int i; } x; x.f = f;
  unsigned int lsb = (x.i >> 16) & 1;
  return (unsigned short)((x.i + 0x7fffu + lsb) >> 16);
}
__device__ inline bf16x8 ld_bf8(const unsigned short* p) { return *(const bf16x8*)p; }

__device__ __forceinline__ void gload_lds16(const unsigned short* gsrc, unsigned short* ldst) {
  __builtin_amdgcn_global_load_lds((const __attribute__((address_space(1))) void*)gsrc,
                                   (__attribute__((address_space(3))) void*)ldst, 16, 0, 0);
}

// ---------------------------------------------------------------------------
__global__ __launch_bounds__(256) void cvt_w4_kernel(const float* __restrict__ wq,
                                                     const float* __restrict__ wk,
                                                     const float* __restrict__ wv,
                                                     const float* __restrict__ wo,
                                                     unsigned short* __restrict__ dq,
                                                     unsigned short* __restrict__ dk,
                                                     unsigned short* __restrict__ dv,
                                                     unsigned short* __restrict__ dwo) {
  int which = blockIdx.y;
  const float* src = which == 0 ? wq : which == 1 ? wk : which == 2 ? wv : wo;
  unsigned short* dst = which == 0 ? dq : which == 1 ? dk : which == 2 ? dv : dwo;
  int i = blockIdx.x * 256 + threadIdx.x;
  const float* s = src + (size_t)i * 8;
  float4 x0 = *(const float4*)(s);
  float4 x1 = *(const float4*)(s + 4);
  ushort8_t u;
  u[0] = f2bf(x0.x); u[1] = f2bf(x0.y); u[2] = f2bf(x0.z); u[3] = f2bf(x0.w);
  u[4] = f2bf(x1.x); u[5] = f2bf(x1.y); u[6] = f2bf(x1.z); u[7] = f2bf(x1.w);
  *(ushort8_t*)(dst + (size_t)i * 8) = u;
}

// ---------------------------------------------------------------------------
// Segment means of x -> xbar (512 threads, 4-way row-quarter reduce);
// also emits xb = bf16(x).
__global__ __launch_bounds__(512) void seg_mean_kernel(const float* __restrict__ x,
                                                       float* __restrict__ xbar,
                                                       unsigned short* __restrict__ xb) {
  int bl = blockIdx.x;
  int b = bl / LM_, l = bl % LM_;
  int t = threadIdx.x;
  int c4 = t & 127;
  int rq = t >> 7;                 // row quarter 0..3 (64 rows each)
  const size_t rowbase = (size_t)b * N_ + (size_t)l * SEG_;
  const float* xp = x + rowbase * C_;
  float4 s = make_float4(0.f, 0.f, 0.f, 0.f);
  for (int r = rq * 64; r < rq * 64 + 64; ++r) {
    float4 v = *(const float4*)(xp + (size_t)r * C_ + c4 * 4);
    s.x += v.x; s.y += v.y; s.z += v.z; s.w += v.w;
    ushort4_t u;
    u[0] = f2bf(v.x); u[1] = f2bf(v.y); u[2] = f2bf(v.z); u[3] = f2bf(v.w);
    *(ushort4_t*)(xb + (rowbase + r) * C_ + c4 * 4) = u;
  }
  __shared__ float red[4][512];
  *(float4*)&red[rq][c4 * 4] = s;
  __syncthreads();
  if (rq == 0) {
    float4 a0 = *(float4*)&red[0][c4 * 4];
    float4 a1 = *(float4*)&red[1][c4 * 4];
    float4 a2 = *(float4*)&red[2][c4 * 4];
    float4 a3 = *(float4*)&red[3][c4 * 4];
    const float invs = 1.0f / SEG_;
    float4 o;
    o.x = ((a0.x + a1.x) + (a2.x + a3.x)) * invs;
    o.y = ((a0.y + a1.y) + (a2.y + a3.y)) * invs;
    o.z = ((a0.z + a1.z) + (a2.z + a3.z)) * invs;
    o.w = ((a0.w + a1.w) + (a2.w + a3.w)) * invs;
    *(float4*)(xbar + (size_t)bl * C_ + c4 * 4) = o;
  }
}

// ---------------------------------------------------------------------------
// Merged landmark projections (f32 VALU GEMM, 128 rows) with bf16 epilogue.
__global__ __launch_bounds__(256) void land_gemm_kernel(const float* __restrict__ xbar,
                                                        const float* __restrict__ wq,
                                                        const float* __restrict__ bq,
                                                        const float* __restrict__ wk,
                                                        const float* __restrict__ bk,
                                                        float* __restrict__ qland,
                                                        float* __restrict__ kland,
                                                        unsigned short* __restrict__ qlbh,
                                                        unsigned short* __restrict__ qlbl,
                                                        unsigned short* __restrict__ klb) {
  __shared__ float As[32][68];
  __shared__ float Ws[32][68];
  int which = blockIdx.x >> 1;
  int row0 = (blockIdx.x & 1) * 64;
  int col0 = blockIdx.y * 64;
  const float* A = xbar;
  const float* W = which ? wk : wq;
  const float* bias = which ? bk : bq;
  float scale = which ? 1.0f : 0.125f;
  float* out = which ? kland : qland;
  int tid = threadIdx.x;
  int tm = tid >> 4, tn = tid & 15;
  float acc[4][4] = {};
  for (int k0 = 0; k0 < C_; k0 += 32) {
#pragma unroll
    for (int i = 0; i < 2; ++i) {
      int s = tid + i * 256;
      int r = s >> 3;
      int kg = (s & 7) << 2;
      float4 av = *(const float4*)(A + (size_t)(row0 + r) * C_ + k0 + kg);
      As[kg + 0][r] = av.x; As[kg + 1][r] = av.y;
      As[kg + 2][r] = av.z; As[kg + 3][r] = av.w;
      float4 wv = *(const float4*)(W + (size_t)(col0 + r) * C_ + k0 + kg);
      Ws[kg + 0][r] = wv.x; Ws[kg + 1][r] = wv.y;
      Ws[kg + 2][r] = wv.z; Ws[kg + 3][r] = wv.w;
    }
    __syncthreads();
#pragma unroll
    for (int kk = 0; kk < 32; ++kk) {
      float4 a = *(const float4*)&As[kk][tm * 4];
      float4 b = *(const float4*)&Ws[kk][tn * 4];
      float av[4] = {a.x, a.y, a.z, a.w};
      float bv[4] = {b.x, b.y, b.z, b.w};
#pragma unroll
      for (int i = 0; i < 4; ++i)
#pragma unroll
        for (int j = 0; j < 4; ++j) acc[i][j] += av[i] * bv[j];
    }
    __syncthreads();
  }
#pragma unroll
  for (int i = 0; i < 4; ++i) {
    int row = row0 + tm * 4 + i;
    int d0 = tn * 4;
    float o4[4];
#pragma unroll
    for (int j = 0; j < 4; ++j) o4[j] = (acc[i][j] + bias[col0 + d0 + j]) * scale;
    int b = row / LM_, n = row % LM_;
    int h = col0 >> 6;
    size_t idx = (((size_t)(b * H_ + h) * LM_) + n) * HD_ + d0;
    float4 o; o.x = o4[0]; o.y = o4[1]; o.z = o4[2]; o.w = o4[3];
    *(float4*)(out + idx) = o;
    if (which == 0) {
      ushort4_t uh, ul;
#pragma unroll
      for (int j = 0; j < 4; ++j) {
        unsigned short hbits = f2bf(o4[j]);
        uh[j] = hbits;
        ul[j] = f2bf(o4[j] - bf2f(hbits));
      }
      *(ushort4_t*)(qlbh + idx) = uh;
      *(ushort4_t*)(qlbl + idx) = ul;
    } else {
      ushort4_t uk;
#pragma unroll
      for (int j = 0; j < 4; ++j) uk[j] = f2bf(o4[j]);
      *(ushort4_t*)(klb + idx) = uk;
    }
  }
}

// ---------------------------------------------------------------------------
// DMA-staged bf16 MFMA GEMM body (ltid in 0..255; per-tile LDS Xs/Wl 8KB each).
__device__ __forceinline__ void dma_gemm_body(const unsigned short* __restrict__ A,
                                              const unsigned short* __restrict__ W,
                                              const float* __restrict__ bias,
                                              void* __restrict__ out,
                                              float scale, int omode,
                                              int row0, int col0,
                                              unsigned short* Xs, unsigned short* Wl,
                                              int tid) {
  int w = tid >> 6, lane = tid & 63;
  int wr = w >> 1, wc = w & 1;
  f32x4 acc[4][4] = {};

  for (int k0 = 0; k0 < C_; k0 += 32) {
    __syncthreads();
#pragma unroll
    for (int i = 0; i < 2; ++i) {
      const unsigned short* gx = A + (size_t)(row0 + w * 32 + i * 16 + (lane >> 2)) * C_ + k0 + (lane & 3) * 8;
      gload_lds16(gx, &Xs[(w * 32 + i * 16) * 32]);
      const unsigned short* gw = W + (size_t)(col0 + w * 32 + i * 16 + (lane >> 2)) * C_ + k0 + (lane & 3) * 8;
      gload_lds16(gw, &Wl[(w * 32 + i * 16) * 32]);
    }
    __syncthreads();
    bf16x8 af[4], bfr[4];
#pragma unroll
    for (int m = 0; m < 4; ++m)
      af[m] = *(bf16x8*)&Xs[(wr * 64 + m * 16 + (lane & 15)) * 32 + (lane >> 4) * 8];
#pragma unroll
    for (int n = 0; n < 4; ++n)
      bfr[n] = *(bf16x8*)&Wl[(wc * 64 + n * 16 + (lane & 15)) * 32 + (lane >> 4) * 8];
#pragma unroll
    for (int m = 0; m < 4; ++m)
#pragma unroll
      for (int n = 0; n < 4; ++n)
        acc[m][n] = __builtin_amdgcn_mfma_f32_16x16x32_bf16(af[m], bfr[n], acc[m][n], 0, 0, 0);
  }

#pragma unroll
  for (int m = 0; m < 4; ++m) {
    int rbase = row0 + wr * 64 + m * 16 + (lane >> 4) * 4;
#pragma unroll
    for (int n = 0; n < 4; ++n) {
      int c = col0 + wc * 64 + n * 16 + (lane & 15);
      float bc = bias[c];
      if (omode == 0) {
#pragma unroll
        for (int rg = 0; rg < 4; ++rg)
          ((float*)out)[(size_t)(rbase + rg) * C_ + c] = acc[m][n][rg] + bc;
      } else if (omode == 2) {
        int b = rbase >> 14, nn = rbase & 16383;
        int h = c >> 6, d = c & 63;
        ushort4_t u;
#pragma unroll
        for (int rg = 0; rg < 4; ++rg) u[rg] = f2bf((acc[m][n][rg] + bc) * scale);
        *(ushort4_t*)((unsigned short*)out + ((size_t)(b * H_ + h) * HD_ + d) * N_ + nn) = u;
      } else {
#pragma unroll
        for (int rg = 0; rg < 4; ++rg) {
          float val = (acc[m][n][rg] + bc) * scale;
          int r = rbase + rg;
          int b = r >> 14, nn = r & 16383, h = c >> 6, d = c & 63;
          ((unsigned short*)out)[(((size_t)(b * H_ + h) * N_) + nn) * HD_ + d] = f2bf(val);
        }
      }
    }
  }
}

// ---------------------------------------------------------------------------
// SVD sweep loop, NW waves (NW*64 threads), RP=64/NW rows per thread.
// LDS: Ac@0 (17408), Vc@17408, pg@34816 (2*NW*256B), pa after pg.
template <int NW>
__device__ __forceinline__ void svd_sweeps(float* a, float* v, char* smemraw,
                                           int w, int lane, int nsweeps) {
  constexpr int RP = 64 / NW;
  float (*Ac)[68] = (float(*)[68])(smemraw);
  float (*Vc)[68] = (float(*)[68])(smemraw + 17408);
  float (*pg)[NW][64] = (float(*)[NW][64])(smemraw + 34816);
  float (*pa)[64] = (float(*)[64])(smemraw + 34816 + 2 * NW * 64 * 4);
  const int r0 = w * RP;
#pragma unroll
  for (int c = 0; c < RP; c += 4) {
    *(float4*)&Ac[lane][r0 + c] = make_float4(a[c], a[c + 1], a[c + 2], a[c + 3]);
    *(float4*)&Vc[lane][r0 + c] = make_float4(v[c], v[c + 1], v[c + 2], v[c + 3]);
  }

  for (int sweep = 0; sweep < nsweeps; ++sweep) {
    float p0 = 0.f, p1 = 0.f;
#pragma unroll
    for (int k = 0; k < RP; k += 2) { p0 = fmaf(a[k], a[k], p0); p1 = fmaf(a[k + 1], a[k + 1], p1); }
    pa[w][lane] = p0 + p1;
    __syncthreads();
    float alpha;
    if constexpr (NW == 4)
      alpha = (pa[0][lane] + pa[1][lane]) + (pa[2][lane] + pa[3][lane]);
    else
      alpha = ((pa[0][lane] + pa[1][lane]) + (pa[2][lane] + pa[3][lane])) +
              ((pa[4][lane] + pa[5][lane]) + (pa[6][lane] + pa[7][lane]));
    for (int mask = 1; mask < 64; ++mask) {
      int buf = mask & 1;
      int partner = lane ^ mask;
      bool lower = lane < partner;
      float beta = __shfl_xor(alpha, mask);
      float o[RP];
#pragma unroll
      for (int c = 0; c < RP; c += 4) {
        float4 t4 = *(float4*)&Ac[partner][r0 + c];
        o[c] = t4.x; o[c + 1] = t4.y; o[c + 2] = t4.z; o[c + 3] = t4.w;
      }
      float g0 = 0.f, g1 = 0.f;
#pragma unroll
      for (int k = 0; k < RP; k += 2) { g0 = fmaf(a[k], o[k], g0); g1 = fmaf(a[k + 1], o[k + 1], g1); }
      pg[buf][w][lane] = g0 + g1;
      __syncthreads();
      float gamma;
      if constexpr (NW == 4)
        gamma = (pg[buf][0][lane] + pg[buf][1][lane]) + (pg[buf][2][lane] + pg[buf][3][lane]);
      else
        gamma = ((pg[buf][0][lane] + pg[buf][1][lane]) + (pg[buf][2][lane] + pg[buf][3][lane])) +
                ((pg[buf][4][lane] + pg[buf][5][lane]) + (pg[buf][6][lane] + pg[buf][7][lane]));
      bool need = (gamma * gamma > 1e-12f * alpha * beta);
      if (__any(need)) {
        float ov[RP];
#pragma unroll
        for (int c = 0; c < RP; c += 4) {
          float4 t4 = *(float4*)&Vc[partner][r0 + c];
          ov[c] = t4.x; ov[c + 1] = t4.y; ov[c + 2] = t4.z; ov[c + 3] = t4.w;
        }
        float ap = lower ? alpha : beta;
        float aq = lower ? beta : alpha;
        float c = 1.f, s = 0.f;
        if (need) {
          float tau = (aq - ap) / (2.f * gamma);
          float t = copysignf(1.f, tau) / (fabsf(tau) + sqrtf(fmaf(tau, tau, 1.f)));
          c = rsqrtf(fmaf(t, t, 1.f));
          s = t * c;
        }
        float sm = lower ? -s : s;
#pragma unroll
        for (int k = 0; k < RP; ++k) a[k] = fmaf(sm, o[k], c * a[k]);
#pragma unroll
        for (int k = 0; k < RP; ++k) v[k] = fmaf(sm, ov[k], c * v[k]);
        float twocsg = 2.f * c * s * gamma;
        alpha = fmaf(c * c, alpha, fmaf(s * s, beta, lower ? -twocsg : twocsg));
#pragma unroll
        for (int cc = 0; cc < RP; cc += 4) {
          *(float4*)&Ac[lane][r0 + cc] = make_float4(a[cc], a[cc + 1], a[cc + 2], a[cc + 3]);
          *(float4*)&Vc[lane][r0 + cc] = make_float4(v[cc], v[cc + 1], v[cc + 2], v[cc + 3]);
        }
      }
    }
  }
}

// Phase 1 (8-wave, 512 threads): ker2 in-LDS, SW1_ sweeps, save state.
__device__ void svd_phase1(const float* __restrict__ qland, const float* __restrict__ kland,
                           float* __restrict__ asave, float* __restrict__ vsave,
                           int bh, char* smemraw, int tid) {
  __builtin_amdgcn_s_setprio(3);
  float (*qlS)[65] = (float(*)[65])(smemraw);
  float (*klS)[65] = (float(*)[65])(smemraw + 16640);
  for (int i = 0; i < 2; ++i) {
    int s = tid + i * 512;
    int r = s >> 4, d4 = (s & 15) << 2;
    *(float4*)&qlS[r][d4] = *(const float4*)(qland + ((size_t)bh * 64 + r) * 64 + d4);
    *(float4*)&klS[r][d4] = *(const float4*)(kland + ((size_t)bh * 64 + r) * 64 + d4);
  }
  __syncthreads();
  int w = tid >> 6, lane = tid & 63;
  float a[8], v[8];
#pragma unroll
  for (int k = 0; k < 8; ++k) {
    int row = w * 8 + k;
    float acc = 0.f;
#pragma unroll
    for (int d4 = 0; d4 < 64; d4 += 4) {
      float4 qv = *(float4*)&qlS[row][d4];
      float4 kv = *(float4*)&klS[lane][d4];
      acc += qv.x * kv.x + qv.y * kv.y + qv.z * kv.z + qv.w * kv.w;
    }
    float e = expf(acc);
    float rs = e;
#pragma unroll
    for (int m = 1; m < 64; m <<= 1) rs += __shfl_xor(rs, m);
    a[k] = e * (1.f / rs);
  }
#pragma unroll
  for (int k = 0; k < 8; ++k) v[k] = (w * 8 + k == lane) ? 1.f : 0.f;
  __syncthreads();   // qlS/klS dead; Ac/Vc overlay safe
  svd_sweeps<8>(a, v, smemraw, w, lane, SW1_);
#pragma unroll
  for (int k = 0; k < 8; ++k) {
    asave[((size_t)bh * 64 + w * 8 + k) * 64 + lane] = a[k];
    vsave[((size_t)bh * 64 + w * 8 + k) * 64 + lane] = v[k];
  }
  __builtin_amdgcn_s_setprio(0);
}

// Phase 2 (8-wave, 512 threads): load state, SW2_ sweeps, sigma/cutoff + pinv.
// LDS: sweeps region 0..40960; ps2 @40960 (4096); vsL/wasL overlay Ac/Vc.
__device__ void svd_phase2(const float* __restrict__ asave, const float* __restrict__ vsave,
                           float* __restrict__ pinv, int bh, char* smemraw, int tid) {
  __builtin_amdgcn_s_setprio(3);
  double (*ps2)[64]  = (double(*)[64])(smemraw + 40960);
  float (*vsL)[65]   = (float(*)[65])(smemraw);
  float (*wasL)[65]  = (float(*)[65])(smemraw + 16640);
  int w = tid >> 6, lane = tid & 63;
  float a[8], v[8];
#pragma unroll
  for (int k = 0; k < 8; ++k) {
    a[k] = asave[((size_t)bh * 64 + w * 8 + k) * 64 + lane];
    v[k] = vsave[((size_t)bh * 64 + w * 8 + k) * 64 + lane];
  }
  svd_sweeps<8>(a, v, smemraw, w, lane, SW2_);

  double psig = 0.0;
#pragma unroll
  for (int k = 0; k < 8; ++k) psig += (double)a[k] * (double)a[k];
  ps2[w][lane] = psig;
  __syncthreads();
  double sig2 = ((ps2[0][lane] + ps2[1][lane]) + (ps2[2][lane] + ps2[3][lane])) +
                ((ps2[4][lane] + ps2[5][lane]) + (ps2[6][lane] + ps2[7][lane]));
  double smax = sig2;
#pragma unroll
  for (int m = 1; m < 64; m <<= 1) smax = fmax(smax, __shfl_xor(smax, m));
  double cutoff2 = smax * (RCOND_ * RCOND_);
  float wgt = (sig2 > cutoff2) ? (float)(1.0 / sig2) : 0.f;

#pragma unroll
  for (int k = 0; k < 8; ++k) {
    vsL[lane][w * 8 + k] = v[k];
    wasL[lane][w * 8 + k] = wgt * a[k];
  }
  __syncthreads();
  // pinv[i][j] = sum_r vsL[r][i] * wasL[r][j]; per-element order unchanged.
  int i = tid >> 3;
  int j0 = (tid & 7) * 8;
  float acc[8] = {};
  for (int r = 0; r < 64; ++r) {
    float vv = vsL[r][i];
#pragma unroll
    for (int jj = 0; jj < 8; ++jj) acc[jj] = fmaf(vv, wasL[r][j0 + jj], acc[jj]);
  }
#pragma unroll
  for (int jj = 0; jj < 8; jj += 4) {
    float4 ovv = make_float4(acc[jj], acc[jj + 1], acc[jj + 2], acc[jj + 3]);
    *(float4*)(pinv + ((size_t)bh * 64 + i) * 64 + j0 + jj) = ovv;
  }
  __builtin_amdgcn_s_setprio(0);
}

// ---------------------------------------------------------------------------
// Fused 1 (512 threads): blocks 0..15 = SVD phase 1 (8-wave);
// blocks 16..1551 = DMA projections, two 128^2 tiles per block.
__global__ __launch_bounds__(512) void fused1_kernel(
    const unsigned short* __restrict__ xb,
    const unsigned short* __restrict__ wqb, const float* __restrict__ bq,
    const unsigned short* __restrict__ wkb, const float* __restrict__ bk,
    const unsigned short* __restrict__ wvb, const float* __restrict__ bv,
    unsigned short* __restrict__ q4, unsigned short* __restrict__ k4,
    unsigned short* __restrict__ vt,
    const float* __restrict__ qland, const float* __restrict__ kland,
    float* __restrict__ asave, float* __restrict__ vsave) {
  __shared__ __align__(16) char smem[40960];
  int tid = threadIdx.x;
  int blk = blockIdx.x;
  if (blk < 16) { svd_phase1(qland, kland, asave, vsave, blk, smem, tid); return; }
  int g = blk - 16;
  int which = g >> 9;          // 512 blocks per projection
  int subpair = g & 511;
  int half = tid >> 8;
  int ltid = tid & 255;
  int sub = subpair * 2 + half;
  int row0 = (sub >> 2) * 128;
  int col0 = (sub & 3) * 128;
  unsigned short* Xs = (unsigned short*)(smem + half * 16384);
  unsigned short* Wl = Xs + 128 * 32;
  if (which == 0)
    dma_gemm_body(xb, wqb, bq, q4, 0.125f, 1, row0, col0, Xs, Wl, ltid);
  else if (which == 1)
    dma_gemm_body(xb, wkb, bk, k4, 1.0f, 1, row0, col0, Xs, Wl, ltid);
  else
    dma_gemm_body(xb, wvb, bv, vt, 1.0f, 2, row0, col0, Xs, Wl, ltid);
}

// ---------------------------------------------------------------------------
// ker3+kv body (deviation form, MFMA); ltid in 0..255; no internal barriers.
__device__ void ker3kv_body(const unsigned short* __restrict__ qlh,
                            const unsigned short* __restrict__ qll,
                            const unsigned short* __restrict__ k4,
                            const unsigned short* __restrict__ vt,
                            float* __restrict__ pacc,
                            float* __restrict__ pacc0,
                            float* __restrict__ ps,
                            int bh, int ch, char* smemraw, int tid) {
  int w = tid >> 6, lane = tid & 63;
  int part = ch * 4 + w;
  int lrow = lane & 15, lgrp = lane >> 4;
  unsigned short* myP = (unsigned short*)smemraw + w * 64 * 72;

  bf16x8 qah[4][2], qal[4][2];
#pragma unroll
  for (int mf = 0; mf < 4; ++mf)
#pragma unroll
    for (int ks = 0; ks < 2; ++ks) {
      size_t off = ((size_t)bh * 64 + mf * 16 + lrow) * 64 + ks * 32 + lgrp * 8;
      qah[mf][ks] = ld_bf8(qlh + off);
      qal[mf][ks] = ld_bf8(qll + off);
    }
  bf16x8 onesf;
#pragma unroll
  for (int j = 0; j < 8; ++j) onesf[j] = (__bf16)1.0f;

  f32x4 kvacc[4][4] = {};
  f32x4 oneacc[4] = {};
  f32x4 ssum[4] = {};

  for (int sub = 0; sub < 4; ++sub) {
    int n0 = ch * 1024 + w * 256 + sub * 64;
    f32x4 sacc[4][4] = {};
#pragma unroll
    for (int ks = 0; ks < 2; ++ks) {
#pragma unroll
      for (int nf = 0; nf < 4; ++nf) {
        bf16x8 kb = ld_bf8(k4 + ((size_t)bh * N_ + n0 + nf * 16 + lrow) * 64 + ks * 32 + lgrp * 8);
#pragma unroll
        for (int mf = 0; mf < 4; ++mf) {
          sacc[mf][nf] = __builtin_amdgcn_mfma_f32_16x16x32_bf16(qah[mf][ks], kb, sacc[mf][nf], 0, 0, 0);
          sacc[mf][nf] = __builtin_amdgcn_mfma_f32_16x16x32_bf16(qal[mf][ks], kb, sacc[mf][nf], 0, 0, 0);
        }
      }
    }
#pragma unroll
    for (int mf = 0; mf < 4; ++mf) {
#pragma unroll
      for (int nf = 0; nf < 4; ++nf) {
#pragma unroll
        for (int r = 0; r < 4; ++r) {
          float pd = expf(sacc[mf][nf][r]) - 1.0f;
          ssum[mf][r] += pd;
          myP[(mf * 16 + lgrp * 4 + r) * 72 + nf * 16 + lrow] = f2bf(pd);
        }
      }
    }
#pragma unroll
    for (int ks = 0; ks < 2; ++ks) {
      bf16x8 pa[4];
#pragma unroll
      for (int mf = 0; mf < 4; ++mf)
        pa[mf] = ld_bf8(myP + (mf * 16 + lrow) * 72 + ks * 32 + lgrp * 8);
#pragma unroll
      for (int nf = 0; nf < 4; ++nf) {
        bf16x8 vb = ld_bf8(vt + ((size_t)bh * 64 + nf * 16 + lrow) * N_ + n0 + ks * 32 + lgrp * 8);
#pragma unroll
        for (int mf = 0; mf < 4; ++mf)
          kvacc[mf][nf] = __builtin_amdgcn_mfma_f32_16x16x32_bf16(pa[mf], vb, kvacc[mf][nf], 0, 0, 0);
        oneacc[nf] = __builtin_amdgcn_mfma_f32_16x16x32_bf16(onesf, vb, oneacc[nf], 0, 0, 0);
      }
    }
  }
#pragma unroll
  for (int mf = 0; mf < 4; ++mf)
#pragma unroll
    for (int m = 1; m < 16; m <<= 1)
#pragma unroll
      for (int r = 0; r < 4; ++r) ssum[mf][r] += __shfl_xor(ssum[mf][r], m);

  size_t pb = (((size_t)bh * NPART_ + part) * 64) * 64;
#pragma unroll
  for (int mf = 0; mf < 4; ++mf)
#pragma unroll
    for (int nf = 0; nf < 4; ++nf)
#pragma unroll
      for (int r = 0; r < 4; ++r)
        pacc[pb + (size_t)(mf * 16 + lgrp * 4 + r) * 64 + nf * 16 + lrow] = kvacc[mf][nf][r];
  if (lrow == 0) {
#pragma unroll
    for (int mf = 0; mf < 4; ++mf)
#pragma unroll
      for (int r = 0; r < 4; ++r)
        ps[((size_t)bh * NPART_ + part) * 64 + mf * 16 + lgrp * 4 + r] = ssum[mf][r];
  }
  if (lgrp == 0) {
#pragma unroll
    for (int nf = 0; nf < 4; ++nf)
      pacc0[((size_t)bh * NPART_ + part) * 64 + nf * 16 + lrow] = oneacc[nf][0];
  }
}

// Fused 2 (512 threads): blocks 0..15 = SVD phase 2 (8-wave);
// blocks 16..143 = ker3kv, two chunks per block (barrier-free body).
__global__ __launch_bounds__(512, 1) void fused2_kernel(
    const unsigned short* __restrict__ qlh,
    const unsigned short* __restrict__ qll,
    const unsigned short* __restrict__ k4,
    const unsigned short* __restrict__ vt,
    float* __restrict__ pacc, float* __restrict__ pacc0, float* __restrict__ ps,
    const float* __restrict__ asave, const float* __restrict__ vsave,
    float* __restrict__ pinv) {
  __shared__ __align__(16) char smem[73728];
  int tid = threadIdx.x;
  int blk = blockIdx.x;
  if (blk < 16) { svd_phase2(asave, vsave, pinv, blk, smem, tid); return; }
  int g = blk - 16;                // 0..127
  int bh = g >> 3, cpair = g & 7;
  int half = tid >> 8;
  int ltid = tid & 255;
  int ch = cpair * 2 + half;
  ker3kv_body(qlh, qll, k4, vt, pacc, pacc0, ps, bh, ch, smem + half * 36864, ltid);
}

// ---------------------------------------------------------------------------
// Fused combine+mmat (identical math/order to split kernels).
__global__ __launch_bounds__(256) void cm_kernel(const float* __restrict__ pacc,
                                                 const float* __restrict__ pacc0,
                                                 const float* __restrict__ ps,
                                                 const float* __restrict__ pinv,
                                                 unsigned short* __restrict__ mtbh,
                                                 unsigned short* __restrict__ mtbl,
                                                 float* __restrict__ msum) {
  int bh = blockIdx.x;
  int tid = threadIdx.x;
  __shared__ float kvs[64][68];
  __shared__ double pcsd[64];
  for (int g = 0; g < 4; ++g) {
    int lm = g * 16 + (tid >> 4);
    int d4 = (tid & 15) * 4;
    float s = 16384.f;
    for (int part = 0; part < NPART_; ++part) s += ps[((size_t)bh * NPART_ + part) * 64 + lm];
    float4 a = make_float4(0.f, 0.f, 0.f, 0.f);
    for (int part = 0; part < NPART_; ++part) {
      float4 c0 = *(const float4*)&pacc0[((size_t)bh * NPART_ + part) * 64 + d4];
      float4 v = *(const float4*)&pacc[(((size_t)bh * NPART_ + part) * 64 + lm) * 64 + d4];
      a.x += c0.x + v.x; a.y += c0.y + v.y; a.z += c0.z + v.z; a.w += c0.w + v.w;
    }
    float inv = 1.f / s;
    kvs[lm][d4 + 0] = a.x * inv; kvs[lm][d4 + 1] = a.y * inv;
    kvs[lm][d4 + 2] = a.z * inv; kvs[lm][d4 + 3] = a.w * inv;
  }
  if (tid < 64) {
    double s = 0.0;
    for (int l = 0; l < 64; ++l) s += (double)pinv[((size_t)bh * 64 + l) * 64 + tid];
    pcsd[tid] = s;
  }
  __syncthreads();
  int l = tid >> 2, t = tid & 3;
  double o[16] = {};
  for (int j = 0; j < 64; ++j) {
    double pv = (double)pinv[((size_t)bh * 64 + l) * 64 + j];
#pragma unroll
    for (int i = 0; i < 16; ++i) o[i] += pv * (double)kvs[j][t * 16 + i];
  }
#pragma unroll
  for (int i = 0; i < 16; ++i) {
    float f = (float)o[i];
    unsigned short hi = f2bf(f);
    float lo = f - bf2f(hi);
    int d = t * 16 + i;
    mtbh[((size_t)bh * 64 + d) * 64 + l] = hi;
    mtbl[((size_t)bh * 64 + d) * 64 + l] = f2bf(lo);
  }
  if (tid < 64) {
    double m = 0.0;
    for (int j = 0; j < 64; ++j) m += pcsd[j] * (double)kvs[j][tid];
    msum[(size_t)bh * 64 + tid] = (float)(m * (1.0 / 64.0));
  }
}

// ---------------------------------------------------------------------------
__global__ __launch_bounds__(256, 1) void ker1out_mfma_kernel(
    const unsigned short* __restrict__ q4,
    const unsigned short* __restrict__ klb,
    const unsigned short* __restrict__ mtbh,
    const unsigned short* __restrict__ mtbl,
    const float* __restrict__ msum,
    unsigned short* __restrict__ outh) {
  int bh = blockIdx.y, tile = blockIdx.x;
  int b = bh >> 3, h = bh & 7;
  int tid = threadIdx.x, w = tid >> 6, lane = tid & 63;
  int lrow = lane & 15, lgrp = lane >> 4;
  int tok0 = tile * 256 + w * 64;
  __shared__ __align__(16) unsigned short Pl[4][64 * 72];
  unsigned short* myP = &Pl[w][0];

  f32x4 sacc[4][4] = {};
#pragma unroll
  for (int ks = 0; ks < 2; ++ks) {
    bf16x8 kb[4];
#pragma unroll
    for (int nf = 0; nf < 4; ++nf)
      kb[nf] = ld_bf8(klb + ((size_t)bh * 64 + nf * 16 + lrow) * 64 + ks * 32 + lgrp * 8);
#pragma unroll
    for (int mf = 0; mf < 4; ++mf) {
      bf16x8 qa = ld_bf8(q4 + ((size_t)bh * N_ + tok0 + mf * 16 + lrow) * 64 + ks * 32 + lgrp * 8);
#pragma unroll
      for (int nf = 0; nf < 4; ++nf)
        sacc[mf][nf] = __builtin_amdgcn_mfma_f32_16x16x32_bf16(qa, kb[nf], sacc[mf][nf], 0, 0, 0);
    }
  }
  f32x4 ssum[4] = {};
#pragma unroll
  for (int mf = 0; mf < 4; ++mf)
#pragma unroll
    for (int nf = 0; nf < 4; ++nf)
#pragma unroll
      for (int r = 0; r < 4; ++r) {
        sacc[mf][nf][r] = expf(sacc[mf][nf][r]);
        ssum[mf][r] += sacc[mf][nf][r];
      }
#pragma unroll
  for (int mf = 0; mf < 4; ++mf)
#pragma unroll
    for (int m = 1; m < 16; m <<= 1)
#pragma unroll
      for (int r = 0; r < 4; ++r) ssum[mf][r] += __shfl_xor(ssum[mf][r], m);
#pragma unroll
  for (int mf = 0; mf < 4; ++mf) {
    f32x4 inv;
#pragma unroll
    for (int r = 0; r < 4; ++r) inv[r] = 1.f / ssum[mf][r];
#pragma unroll
    for (int nf = 0; nf < 4; ++nf)
#pragma unroll
      for (int r = 0; r < 4; ++r) {
        float pdev = fmaf(sacc[mf][nf][r], inv[r], -0.015625f);
        myP[(mf * 16 + lgrp * 4 + r) * 72 + nf * 16 + lrow] = f2bf(pdev);
      }
  }

  f32x4 oacc[4][4] = {};
#pragma unroll
  for (int ks = 0; ks < 2; ++ks) {
    bf16x8 pa[4];
#pragma unroll
    for (int mf = 0; mf < 4; ++mf)
      pa[mf] = ld_bf8(myP + (mf * 16 + lrow) * 72 + ks * 32 + lgrp * 8);
#pragma unroll
    for (int nf = 0; nf < 4; ++nf) {
      bf16x8 mh = ld_bf8(mtbh + ((size_t)bh * 64 + nf * 16 + lrow) * 64 + ks * 32 + lgrp * 8);
      bf16x8 ml = ld_bf8(mtbl + ((size_t)bh * 64 + nf * 16 + lrow) * 64 + ks * 32 + lgrp * 8);
#pragma unroll
      for (int mf = 0; mf < 4; ++mf) {
        oacc[mf][nf] = __builtin_amdgcn_mfma_f32_16x16x32_bf16(pa[mf], mh, oacc[mf][nf], 0, 0, 0);
        oacc[mf][nf] = __builtin_amdgcn_mfma_f32_16x16x32_bf16(pa[mf], ml, oacc[mf][nf], 0, 0, 0);
      }
    }
  }
#pragma unroll
  for (int nf = 0; nf < 4; ++nf) {
    float ms = msum[(size_t)bh * 64 + nf * 16 + lrow];
#pragma unroll
    for (int mf = 0; mf < 4; ++mf)
#pragma unroll
      for (int r = 0; r < 4; ++r) {
        int tok = tok0 + mf * 16 + lgrp * 4 + r;
        int d = nf * 16 + lrow;
        outh[((size_t)b * N_ + tok) * C_ + h * HD_ + d] = f2bf(oacc[mf][nf][r] + ms);
      }
  }
}

// ---------------------------------------------------------------------------
// Final projection (serial tail): outh(bf16) @ wob^T(bf16) + bo -> f32 out.
__global__ __launch_bounds__(256) void oproj_kernel(const unsigned short* __restrict__ outh,
                                                    const unsigned short* __restrict__ wob,
                                                    const float* __restrict__ bo,
                                                    float* __restrict__ out) {
  __shared__ __align__(16) unsigned short Xs[128 * 32];
  __shared__ __align__(16) unsigned short Wl[128 * 32];
  dma_gemm_body(outh, wob, bo, out, 1.0f, 0, blockIdx.x * 128, blockIdx.y * 128,
                Xs, Wl, threadIdx.x);
}

// ---------------------------------------------------------------------------
extern "C" void kernel_launch(void* const* d_in, const int* in_sizes, int n_in,
                              void* d_out, int out_size, void* d_ws, size_t ws_size,
                              hipStream_t stream) {
  const float* x  = (const float*)d_in[0];
  const float* wq = (const float*)d_in[1];
  const float* bq = (const float*)d_in[2];
  const float* wk = (const float*)d_in[3];
  const float* bk = (const float*)d_in[4];
  const float* wv = (const float*)d_in[5];
  const float* bv = (const float*)d_in[6];
  const float* wo = (const float*)d_in[7];
  const float* bo = (const float*)d_in[8];
  float* out = (float*)d_out;

  char* base = (char*)d_ws;
  const size_t QKV = (size_t)BH_ * N_ * HD_;
  unsigned short* q4 = (unsigned short*)base;                 // 32MB
  unsigned short* k4 = (unsigned short*)(base + QKV * 2);     // 32MB
  unsigned short* vt = (unsigned short*)(base + QKV * 4);     // 32MB
  unsigned short* outh = (unsigned short*)(base + QKV * 2);   // alias k4 (dead after ker3kv)
  char* sp = base + QKV * 6;
  float* pacc  = (float*)sp; sp += (size_t)BH_ * NPART_ * 64 * 64 * 4;  // 16.78MB
  float* pacc0 = (float*)sp; sp += (size_t)BH_ * NPART_ * 64 * 4;
  float* ps    = (float*)sp; sp += (size_t)BH_ * NPART_ * 64 * 4;
  float* xbar  = (float*)sp; sp += (size_t)B_ * LM_ * C_ * 4;
  float* qland = (float*)sp; sp += (size_t)BH_ * LM_ * HD_ * 4;
  float* kland = (float*)sp; sp += (size_t)BH_ * LM_ * HD_ * 4;
  unsigned short* qlbh = (unsigned short*)sp; sp += (size_t)BH_ * LM_ * HD_ * 2;
  unsigned short* qlbl = (unsigned short*)sp; sp += (size_t)BH_ * LM_ * HD_ * 2;
  unsigned short* klb  = (unsigned short*)sp; sp += (size_t)BH_ * LM_ * HD_ * 2;
  float* pinv  = (float*)sp; sp += (size_t)BH_ * LM_ * LM_ * 4;
  unsigned short* mtbh = (unsigned short*)sp; sp += (size_t)BH_ * LM_ * HD_ * 2;
  unsigned short* mtbl = (unsigned short*)sp; sp += (size_t)BH_ * LM_ * HD_ * 2;
  float* msum  = (float*)sp; sp += (size_t)BH_ * HD_ * 4;
  float* asave = (float*)sp; sp += (size_t)BH_ * LM_ * LM_ * 4;   // 256KB
  float* vsave = (float*)sp; sp += (size_t)BH_ * LM_ * LM_ * 4;   // 256KB
  unsigned short* wob = (unsigned short*)sp; sp += (size_t)C_ * C_ * 2;  // 512KB
  unsigned short* wqb = (unsigned short*)sp; sp += (size_t)C_ * C_ * 2;  // 512KB
  unsigned short* wkb = (unsigned short*)sp; sp += (size_t)C_ * C_ * 2;  // 512KB
  unsigned short* wvb = (unsigned short*)sp; sp += (size_t)C_ * C_ * 2;  // 512KB

  // xb (bf16 x, 32MB) lives in d_out's first half (dead until oproj).
  unsigned short* xb = (unsigned short*)d_out;

  const int W8 = (C_ * C_) / 8;

  dim3 gc(W8 / 256, 4);
  cvt_w4_kernel<<<gc, 256, 0, stream>>>(wq, wk, wv, wo, wqb, wkb, wvb, wob);

  seg_mean_kernel<<<B_ * LM_, 512, 0, stream>>>(x, xbar, xb);
  dim3 gl(4, 8);
  land_gemm_kernel<<<gl, 256, 0, stream>>>(xbar, wq, bq, wk, bk,
                                           qland, kland, qlbh, qlbl, klb);

  // fused 1: SVD phase 1 (8-wave, 3 sweeps) + DMA projections (2 tiles/blk)
  fused1_kernel<<<16 + 3 * 512, 512, 0, stream>>>(
      xb, wqb, bq, wkb, bk, wvb, bv, q4, k4, vt, qland, kland, asave, vsave);

  // fused 2: SVD phase 2 (8-wave, 2 sweeps + pinv) + ker3kv (2 chunks/blk)
  fused2_kernel<<<16 + BH_ * 8, 512, 0, stream>>>(
      qlbh, qlbl, k4, vt, pacc, pacc0, ps, asave, vsave, pinv);

  // combine + M (fused)
  cm_kernel<<<BH_, 256, 0, stream>>>(pacc, pacc0, ps, pinv, mtbh, mtbl, msum);

  dim3 g9(N_ / 256, BH_);
  ker1out_mfma_kernel<<<g9, 256, 0, stream>>>(q4, klb, mtbh, mtbl, msum, outh);

  dim3 g10(B_ * N_ / 128, C_ / 128);
  oproj_kernel<<<g10, 256, 0, stream>>>(outh, wob, bo, out);
}

// Round 21
// 385.619 us; speedup vs baseline: 1.1630x; 1.0172x over previous
//
#include <hip/hip_runtime.h>
#include <stdint.h>

// NystromAttention MI355X — Round 21: BK=64 for DMA GEMMs (proj + oproj).
// Bitwise-safe: per-acc MFMA K-slice order unchanged (ks=0,1 inside each
// 64-wide k-block preserves the global 0..15 slice sequence); halves the
// barrier count (8 vs 16 double-barriers) and doubles VMEM depth per phase.
// Everything else byte-identical to R20 (passed, 392us, absmax 1.9836e-4).

constexpr int B_   = 2;
constexpr int N_   = 16384;
constexpr int C_   = 512;
constexpr int H_   = 8;
constexpr int HD_  = 64;
constexpr int LM_  = 64;
constexpr int SEG_ = 256;
constexpr int BH_  = 16;
constexpr int NCH_ = 16;
constexpr int NPART_ = 64;
constexpr int SW1_ = 3;   // sweeps in phase 1 (8-wave)
constexpr int SW2_ = 2;   // sweeps in phase 2 (8-wave); total 5

#define RCOND_ (640.0 * 1.1920928955078125e-07)

typedef unsigned short ushort4_t __attribute__((ext_vector_type(4)));
typedef unsigned short ushort8_t __attribute__((ext_vector_type(8)));
typedef __bf16 bf16x8 __attribute__((ext_vector_type(8)));
typedef float f32x4 __attribute__((ext_vector_type(4)));

__device__ inline float bf2f(unsigned short u) {
  union { unsigned int i; float f; } x; x.i = ((unsigned int)u) << 16; return x.f;
}
__device__ inline unsigned short f2bf(float f) {
  union { float f; unsigned int i; } x; x.f = f;
  unsigned int lsb = (x.i >> 16) & 1;
  return (unsigned short)((x.i + 0x7fffu + lsb) >> 16);
}
__device__ inline bf16x8 ld_bf8(const unsigned short* p) { return *(const bf16x8*)p; }

__device__ __forceinline__ void gload_lds16(const unsigned short* gsrc, unsigned short* ldst) {
  __builtin_amdgcn_global_load_lds((const __attribute__((address_space(1))) void*)gsrc,
                                   (__attribute__((address_space(3))) void*)ldst, 16, 0, 0);
}

// ---------------------------------------------------------------------------
__global__ __launch_bounds__(256) void cvt_w4_kernel(const float* __restrict__ wq,
                                                     const float* __restrict__ wk,
                                                     const float* __restrict__ wv,
                                                     const float* __restrict__ wo,
                                                     unsigned short* __restrict__ dq,
                                                     unsigned short* __restrict__ dk,
                                                     unsigned short* __restrict__ dv,
                                                     unsigned short* __restrict__ dwo) {
  int which = blockIdx.y;
  const float* src = which == 0 ? wq : which == 1 ? wk : which == 2 ? wv : wo;
  unsigned short* dst = which == 0 ? dq : which == 1 ? dk : which == 2 ? dv : dwo;
  int i = blockIdx.x * 256 + threadIdx.x;
  const float* s = src + (size_t)i * 8;
  float4 x0 = *(const float4*)(s);
  float4 x1 = *(const float4*)(s + 4);
  ushort8_t u;
  u[0] = f2bf(x0.x); u[1] = f2bf(x0.y); u[2] = f2bf(x0.z); u[3] = f2bf(x0.w);
  u[4] = f2bf(x1.x); u[5] = f2bf(x1.y); u[6] = f2bf(x1.z); u[7] = f2bf(x1.w);
  *(ushort8_t*)(dst + (size_t)i * 8) = u;
}

// ---------------------------------------------------------------------------
// Segment means of x -> xbar (512 threads, 4-way row-quarter reduce);
// also emits xb = bf16(x).
__global__ __launch_bounds__(512) void seg_mean_kernel(const float* __restrict__ x,
                                                       float* __restrict__ xbar,
                                                       unsigned short* __restrict__ xb) {
  int bl = blockIdx.x;
  int b = bl / LM_, l = bl % LM_;
  int t = threadIdx.x;
  int c4 = t & 127;
  int rq = t >> 7;                 // row quarter 0..3 (64 rows each)
  const size_t rowbase = (size_t)b * N_ + (size_t)l * SEG_;
  const float* xp = x + rowbase * C_;
  float4 s = make_float4(0.f, 0.f, 0.f, 0.f);
  for (int r = rq * 64; r < rq * 64 + 64; ++r) {
    float4 v = *(const float4*)(xp + (size_t)r * C_ + c4 * 4);
    s.x += v.x; s.y += v.y; s.z += v.z; s.w += v.w;
    ushort4_t u;
    u[0] = f2bf(v.x); u[1] = f2bf(v.y); u[2] = f2bf(v.z); u[3] = f2bf(v.w);
    *(ushort4_t*)(xb + (rowbase + r) * C_ + c4 * 4) = u;
  }
  __shared__ float red[4][512];
  *(float4*)&red[rq][c4 * 4] = s;
  __syncthreads();
  if (rq == 0) {
    float4 a0 = *(float4*)&red[0][c4 * 4];
    float4 a1 = *(float4*)&red[1][c4 * 4];
    float4 a2 = *(float4*)&red[2][c4 * 4];
    float4 a3 = *(float4*)&red[3][c4 * 4];
    const float invs = 1.0f / SEG_;
    float4 o;
    o.x = ((a0.x + a1.x) + (a2.x + a3.x)) * invs;
    o.y = ((a0.y + a1.y) + (a2.y + a3.y)) * invs;
    o.z = ((a0.z + a1.z) + (a2.z + a3.z)) * invs;
    o.w = ((a0.w + a1.w) + (a2.w + a3.w)) * invs;
    *(float4*)(xbar + (size_t)bl * C_ + c4 * 4) = o;
  }
}

// ---------------------------------------------------------------------------
// Merged landmark projections (f32 VALU GEMM, 128 rows) with bf16 epilogue.
__global__ __launch_bounds__(256) void land_gemm_kernel(const float* __restrict__ xbar,
                                                        const float* __restrict__ wq,
                                                        const float* __restrict__ bq,
                                                        const float* __restrict__ wk,
                                                        const float* __restrict__ bk,
                                                        float* __restrict__ qland,
                                                        float* __restrict__ kland,
                                                        unsigned short* __restrict__ qlbh,
                                                        unsigned short* __restrict__ qlbl,
                                                        unsigned short* __restrict__ klb) {
  __shared__ float As[32][68];
  __shared__ float Ws[32][68];
  int which = blockIdx.x >> 1;
  int row0 = (blockIdx.x & 1) * 64;
  int col0 = blockIdx.y * 64;
  const float* A = xbar;
  const float* W = which ? wk : wq;
  const float* bias = which ? bk : bq;
  float scale = which ? 1.0f : 0.125f;
  float* out = which ? kland : qland;
  int tid = threadIdx.x;
  int tm = tid >> 4, tn = tid & 15;
  float acc[4][4] = {};
  for (int k0 = 0; k0 < C_; k0 += 32) {
#pragma unroll
    for (int i = 0; i < 2; ++i) {
      int s = tid + i * 256;
      int r = s >> 3;
      int kg = (s & 7) << 2;
      float4 av = *(const float4*)(A + (size_t)(row0 + r) * C_ + k0 + kg);
      As[kg + 0][r] = av.x; As[kg + 1][r] = av.y;
      As[kg + 2][r] = av.z; As[kg + 3][r] = av.w;
      float4 wv = *(const float4*)(W + (size_t)(col0 + r) * C_ + k0 + kg);
      Ws[kg + 0][r] = wv.x; Ws[kg + 1][r] = wv.y;
      Ws[kg + 2][r] = wv.z; Ws[kg + 3][r] = wv.w;
    }
    __syncthreads();
#pragma unroll
    for (int kk = 0; kk < 32; ++kk) {
      float4 a = *(const float4*)&As[kk][tm * 4];
      float4 b = *(const float4*)&Ws[kk][tn * 4];
      float av[4] = {a.x, a.y, a.z, a.w};
      float bv[4] = {b.x, b.y, b.z, b.w};
#pragma unroll
      for (int i = 0; i < 4; ++i)
#pragma unroll
        for (int j = 0; j < 4; ++j) acc[i][j] += av[i] * bv[j];
    }
    __syncthreads();
  }
#pragma unroll
  for (int i = 0; i < 4; ++i) {
    int row = row0 + tm * 4 + i;
    int d0 = tn * 4;
    float o4[4];
#pragma unroll
    for (int j = 0; j < 4; ++j) o4[j] = (acc[i][j] + bias[col0 + d0 + j]) * scale;
    int b = row / LM_, n = row % LM_;
    int h = col0 >> 6;
    size_t idx = (((size_t)(b * H_ + h) * LM_) + n) * HD_ + d0;
    float4 o; o.x = o4[0]; o.y = o4[1]; o.z = o4[2]; o.w = o4[3];
    *(float4*)(out + idx) = o;
    if (which == 0) {
      ushort4_t uh, ul;
#pragma unroll
      for (int j = 0; j < 4; ++j) {
        unsigned short hbits = f2bf(o4[j]);
        uh[j] = hbits;
        ul[j] = f2bf(o4[j] - bf2f(hbits));
      }
      *(ushort4_t*)(qlbh + idx) = uh;
      *(ushort4_t*)(qlbl + idx) = ul;
    } else {
      ushort4_t uk;
#pragma unroll
      for (int j = 0; j < 4; ++j) uk[j] = f2bf(o4[j]);
      *(ushort4_t*)(klb + idx) = uk;
    }
  }
}

// ---------------------------------------------------------------------------
// DMA-staged bf16 MFMA GEMM body, BK=64 (ltid 0..255; LDS Xs/Wl 16KB each).
// Per-acc MFMA K-slice order identical to BK=32 version (bitwise-safe).
__device__ __forceinline__ void dma_gemm_body(const unsigned short* __restrict__ A,
                                              const unsigned short* __restrict__ W,
                                              const float* __restrict__ bias,
                                              void* __restrict__ out,
                                              float scale, int omode,
                                              int row0, int col0,
                                              unsigned short* Xs, unsigned short* Wl,
                                              int tid) {
  int w = tid >> 6, lane = tid & 63;
  int wr = w >> 1, wc = w & 1;
  f32x4 acc[4][4] = {};

  for (int k0 = 0; k0 < C_; k0 += 64) {
    __syncthreads();
    // stage 128x64 bf16 tiles: 4 passes of 32 rows; lane covers one row-eighth
#pragma unroll
    for (int i = 0; i < 4; ++i) {
      int r = i * 32 + w * 8 + (lane >> 3);
      int c8 = (lane & 7) * 8;
      gload_lds16(A + (size_t)(row0 + r) * C_ + k0 + c8, &Xs[(i * 32 + w * 8) * 64]);
      gload_lds16(W + (size_t)(col0 + r) * C_ + k0 + c8, &Wl[(i * 32 + w * 8) * 64]);
    }
    __syncthreads();
    bf16x8 af[4][2], bfr[4][2];
#pragma unroll
    for (int m = 0; m < 4; ++m) {
      af[m][0] = *(bf16x8*)&Xs[(wr * 64 + m * 16 + (lane & 15)) * 64 + (lane >> 4) * 8];
      af[m][1] = *(bf16x8*)&Xs[(wr * 64 + m * 16 + (lane & 15)) * 64 + 32 + (lane >> 4) * 8];
    }
#pragma unroll
    for (int n = 0; n < 4; ++n) {
      bfr[n][0] = *(bf16x8*)&Wl[(wc * 64 + n * 16 + (lane & 15)) * 64 + (lane >> 4) * 8];
      bfr[n][1] = *(bf16x8*)&Wl[(wc * 64 + n * 16 + (lane & 15)) * 64 + 32 + (lane >> 4) * 8];
    }
#pragma unroll
    for (int ks = 0; ks < 2; ++ks)
#pragma unroll
      for (int m = 0; m < 4; ++m)
#pragma unroll
        for (int n = 0; n < 4; ++n)
          acc[m][n] = __builtin_amdgcn_mfma_f32_16x16x32_bf16(af[m][ks], bfr[n][ks], acc[m][n], 0, 0, 0);
  }

#pragma unroll
  for (int m = 0; m < 4; ++m) {
    int rbase = row0 + wr * 64 + m * 16 + (lane >> 4) * 4;
#pragma unroll
    for (int n = 0; n < 4; ++n) {
      int c = col0 + wc * 64 + n * 16 + (lane & 15);
      float bc = bias[c];
      if (omode == 0) {
#pragma unroll
        for (int rg = 0; rg < 4; ++rg)
          ((float*)out)[(size_t)(rbase + rg) * C_ + c] = acc[m][n][rg] + bc;
      } else if (omode == 2) {
        int b = rbase >> 14, nn = rbase & 16383;
        int h = c >> 6, d = c & 63;
        ushort4_t u;
#pragma unroll
        for (int rg = 0; rg < 4; ++rg) u[rg] = f2bf((acc[m][n][rg] + bc) * scale);
        *(ushort4_t*)((unsigned short*)out + ((size_t)(b * H_ + h) * HD_ + d) * N_ + nn) = u;
      } else {
#pragma unroll
        for (int rg = 0; rg < 4; ++rg) {
          float val = (acc[m][n][rg] + bc) * scale;
          int r = rbase + rg;
          int b = r >> 14, nn = r & 16383, h = c >> 6, d = c & 63;
          ((unsigned short*)out)[(((size_t)(b * H_ + h) * N_) + nn) * HD_ + d] = f2bf(val);
        }
      }
    }
  }
}

// ---------------------------------------------------------------------------
// SVD sweep loop, NW waves (NW*64 threads), RP=64/NW rows per thread.
// LDS: Ac@0 (17408), Vc@17408, pg@34816 (2*NW*256B), pa after pg.
template <int NW>
__device__ __forceinline__ void svd_sweeps(float* a, float* v, char* smemraw,
                                           int w, int lane, int nsweeps) {
  constexpr int RP = 64 / NW;
  float (*Ac)[68] = (float(*)[68])(smemraw);
  float (*Vc)[68] = (float(*)[68])(smemraw + 17408);
  float (*pg)[NW][64] = (float(*)[NW][64])(smemraw + 34816);
  float (*pa)[64] = (float(*)[64])(smemraw + 34816 + 2 * NW * 64 * 4);
  const int r0 = w * RP;
#pragma unroll
  for (int c = 0; c < RP; c += 4) {
    *(float4*)&Ac[lane][r0 + c] = make_float4(a[c], a[c + 1], a[c + 2], a[c + 3]);
    *(float4*)&Vc[lane][r0 + c] = make_float4(v[c], v[c + 1], v[c + 2], v[c + 3]);
  }

  for (int sweep = 0; sweep < nsweeps; ++sweep) {
    float p0 = 0.f, p1 = 0.f;
#pragma unroll
    for (int k = 0; k < RP; k += 2) { p0 = fmaf(a[k], a[k], p0); p1 = fmaf(a[k + 1], a[k + 1], p1); }
    pa[w][lane] = p0 + p1;
    __syncthreads();
    float alpha;
    if constexpr (NW == 4)
      alpha = (pa[0][lane] + pa[1][lane]) + (pa[2][lane] + pa[3][lane]);
    else
      alpha = ((pa[0][lane] + pa[1][lane]) + (pa[2][lane] + pa[3][lane])) +
              ((pa[4][lane] + pa[5][lane]) + (pa[6][lane] + pa[7][lane]));
    for (int mask = 1; mask < 64; ++mask) {
      int buf = mask & 1;
      int partner = lane ^ mask;
      bool lower = lane < partner;
      float beta = __shfl_xor(alpha, mask);
      float o[RP];
#pragma unroll
      for (int c = 0; c < RP; c += 4) {
        float4 t4 = *(float4*)&Ac[partner][r0 + c];
        o[c] = t4.x; o[c + 1] = t4.y; o[c + 2] = t4.z; o[c + 3] = t4.w;
      }
      float g0 = 0.f, g1 = 0.f;
#pragma unroll
      for (int k = 0; k < RP; k += 2) { g0 = fmaf(a[k], o[k], g0); g1 = fmaf(a[k + 1], o[k + 1], g1); }
      pg[buf][w][lane] = g0 + g1;
      __syncthreads();
      float gamma;
      if constexpr (NW == 4)
        gamma = (pg[buf][0][lane] + pg[buf][1][lane]) + (pg[buf][2][lane] + pg[buf][3][lane]);
      else
        gamma = ((pg[buf][0][lane] + pg[buf][1][lane]) + (pg[buf][2][lane] + pg[buf][3][lane])) +
                ((pg[buf][4][lane] + pg[buf][5][lane]) + (pg[buf][6][lane] + pg[buf][7][lane]));
      bool need = (gamma * gamma > 1e-12f * alpha * beta);
      if (__any(need)) {
        float ov[RP];
#pragma unroll
        for (int c = 0; c < RP; c += 4) {
          float4 t4 = *(float4*)&Vc[partner][r0 + c];
          ov[c] = t4.x; ov[c + 1] = t4.y; ov[c + 2] = t4.z; ov[c + 3] = t4.w;
        }
        float ap = lower ? alpha : beta;
        float aq = lower ? beta : alpha;
        float c = 1.f, s = 0.f;
        if (need) {
          float tau = (aq - ap) / (2.f * gamma);
          float t = copysignf(1.f, tau) / (fabsf(tau) + sqrtf(fmaf(tau, tau, 1.f)));
          c = rsqrtf(fmaf(t, t, 1.f));
          s = t * c;
        }
        float sm = lower ? -s : s;
#pragma unroll
        for (int k = 0; k < RP; ++k) a[k] = fmaf(sm, o[k], c * a[k]);
#pragma unroll
        for (int k = 0; k < RP; ++k) v[k] = fmaf(sm, ov[k], c * v[k]);
        float twocsg = 2.f * c * s * gamma;
        alpha = fmaf(c * c, alpha, fmaf(s * s, beta, lower ? -twocsg : twocsg));
#pragma unroll
        for (int cc = 0; cc < RP; cc += 4) {
          *(float4*)&Ac[lane][r0 + cc] = make_float4(a[cc], a[cc + 1], a[cc + 2], a[cc + 3]);
          *(float4*)&Vc[lane][r0 + cc] = make_float4(v[cc], v[cc + 1], v[cc + 2], v[cc + 3]);
        }
      }
    }
  }
}

// Phase 1 (8-wave, 512 threads): ker2 in-LDS, SW1_ sweeps, save state.
__device__ void svd_phase1(const float* __restrict__ qland, const float* __restrict__ kland,
                           float* __restrict__ asave, float* __restrict__ vsave,
                           int bh, char* smemraw, int tid) {
  __builtin_amdgcn_s_setprio(3);
  float (*qlS)[65] = (float(*)[65])(smemraw);
  float (*klS)[65] = (float(*)[65])(smemraw + 16640);
  for (int i = 0; i < 2; ++i) {
    int s = tid + i * 512;
    int r = s >> 4, d4 = (s & 15) << 2;
    *(float4*)&qlS[r][d4] = *(const float4*)(qland + ((size_t)bh * 64 + r) * 64 + d4);
    *(float4*)&klS[r][d4] = *(const float4*)(kland + ((size_t)bh * 64 + r) * 64 + d4);
  }
  __syncthreads();
  int w = tid >> 6, lane = tid & 63;
  float a[8], v[8];
#pragma unroll
  for (int k = 0; k < 8; ++k) {
    int row = w * 8 + k;
    float acc = 0.f;
#pragma unroll
    for (int d4 = 0; d4 < 64; d4 += 4) {
      float4 qv = *(float4*)&qlS[row][d4];
      float4 kv = *(float4*)&klS[lane][d4];
      acc += qv.x * kv.x + qv.y * kv.y + qv.z * kv.z + qv.w * kv.w;
    }
    float e = expf(acc);
    float rs = e;
#pragma unroll
    for (int m = 1; m < 64; m <<= 1) rs += __shfl_xor(rs, m);
    a[k] = e * (1.f / rs);
  }
#pragma unroll
  for (int k = 0; k < 8; ++k) v[k] = (w * 8 + k == lane) ? 1.f : 0.f;
  __syncthreads();   // qlS/klS dead; Ac/Vc overlay safe
  svd_sweeps<8>(a, v, smemraw, w, lane, SW1_);
#pragma unroll
  for (int k = 0; k < 8; ++k) {
    asave[((size_t)bh * 64 + w * 8 + k) * 64 + lane] = a[k];
    vsave[((size_t)bh * 64 + w * 8 + k) * 64 + lane] = v[k];
  }
  __builtin_amdgcn_s_setprio(0);
}

// Phase 2 (8-wave, 512 threads): load state, SW2_ sweeps, sigma/cutoff + pinv.
__device__ void svd_phase2(const float* __restrict__ asave, const float* __restrict__ vsave,
                           float* __restrict__ pinv, int bh, char* smemraw, int tid) {
  __builtin_amdgcn_s_setprio(3);
  double (*ps2)[64]  = (double(*)[64])(smemraw + 40960);
  float (*vsL)[65]   = (float(*)[65])(smemraw);
  float (*wasL)[65]  = (float(*)[65])(smemraw + 16640);
  int w = tid >> 6, lane = tid & 63;
  float a[8], v[8];
#pragma unroll
  for (int k = 0; k < 8; ++k) {
    a[k] = asave[((size_t)bh * 64 + w * 8 + k) * 64 + lane];
    v[k] = vsave[((size_t)bh * 64 + w * 8 + k) * 64 + lane];
  }
  svd_sweeps<8>(a, v, smemraw, w, lane, SW2_);

  double psig = 0.0;
#pragma unroll
  for (int k = 0; k < 8; ++k) psig += (double)a[k] * (double)a[k];
  ps2[w][lane] = psig;
  __syncthreads();
  double sig2 = ((ps2[0][lane] + ps2[1][lane]) + (ps2[2][lane] + ps2[3][lane])) +
                ((ps2[4][lane] + ps2[5][lane]) + (ps2[6][lane] + ps2[7][lane]));
  double smax = sig2;
#pragma unroll
  for (int m = 1; m < 64; m <<= 1) smax = fmax(smax, __shfl_xor(smax, m));
  double cutoff2 = smax * (RCOND_ * RCOND_);
  float wgt = (sig2 > cutoff2) ? (float)(1.0 / sig2) : 0.f;

#pragma unroll
  for (int k = 0; k < 8; ++k) {
    vsL[lane][w * 8 + k] = v[k];
    wasL[lane][w * 8 + k] = wgt * a[k];
  }
  __syncthreads();
  int i = tid >> 3;
  int j0 = (tid & 7) * 8;
  float acc[8] = {};
  for (int r = 0; r < 64; ++r) {
    float vv = vsL[r][i];
#pragma unroll
    for (int jj = 0; jj < 8; ++jj) acc[jj] = fmaf(vv, wasL[r][j0 + jj], acc[jj]);
  }
#pragma unroll
  for (int jj = 0; jj < 8; jj += 4) {
    float4 ovv = make_float4(acc[jj], acc[jj + 1], acc[jj + 2], acc[jj + 3]);
    *(float4*)(pinv + ((size_t)bh * 64 + i) * 64 + j0 + jj) = ovv;
  }
  __builtin_amdgcn_s_setprio(0);
}

// ---------------------------------------------------------------------------
// Fused 1 (512 threads): blocks 0..15 = SVD phase 1 (8-wave);
// blocks 16..1551 = DMA projections (BK=64), two 128^2 tiles per block.
__global__ __launch_bounds__(512) void fused1_kernel(
    const unsigned short* __restrict__ xb,
    const unsigned short* __restrict__ wqb, const float* __restrict__ bq,
    const unsigned short* __restrict__ wkb, const float* __restrict__ bk,
    const unsigned short* __restrict__ wvb, const float* __restrict__ bv,
    unsigned short* __restrict__ q4, unsigned short* __restrict__ k4,
    unsigned short* __restrict__ vt,
    const float* __restrict__ qland, const float* __restrict__ kland,
    float* __restrict__ asave, float* __restrict__ vsave) {
  __shared__ __align__(16) char smem[65536];
  int tid = threadIdx.x;
  int blk = blockIdx.x;
  if (blk < 16) { svd_phase1(qland, kland, asave, vsave, blk, smem, tid); return; }
  int g = blk - 16;
  int which = g >> 9;          // 512 blocks per projection
  int subpair = g & 511;
  int half = tid >> 8;
  int ltid = tid & 255;
  int sub = subpair * 2 + half;
  int row0 = (sub >> 2) * 128;
  int col0 = (sub & 3) * 128;
  unsigned short* Xs = (unsigned short*)(smem + half * 32768);
  unsigned short* Wl = Xs + 128 * 64;
  if (which == 0)
    dma_gemm_body(xb, wqb, bq, q4, 0.125f, 1, row0, col0, Xs, Wl, ltid);
  else if (which == 1)
    dma_gemm_body(xb, wkb, bk, k4, 1.0f, 1, row0, col0, Xs, Wl, ltid);
  else
    dma_gemm_body(xb, wvb, bv, vt, 1.0f, 2, row0, col0, Xs, Wl, ltid);
}

// ---------------------------------------------------------------------------
// ker3+kv body (deviation form, MFMA); ltid in 0..255; no internal barriers.
__device__ void ker3kv_body(const unsigned short* __restrict__ qlh,
                            const unsigned short* __restrict__ qll,
                            const unsigned short* __restrict__ k4,
                            const unsigned short* __restrict__ vt,
                            float* __restrict__ pacc,
                            float* __restrict__ pacc0,
                            float* __restrict__ ps,
                            int bh, int ch, char* smemraw, int tid) {
  int w = tid >> 6, lane = tid & 63;
  int part = ch * 4 + w;
  int lrow = lane & 15, lgrp = lane >> 4;
  unsigned short* myP = (unsigned short*)smemraw + w * 64 * 72;

  bf16x8 qah[4][2], qal[4][2];
#pragma unroll
  for (int mf = 0; mf < 4; ++mf)
#pragma unroll
    for (int ks = 0; ks < 2; ++ks) {
      size_t off = ((size_t)bh * 64 + mf * 16 + lrow) * 64 + ks * 32 + lgrp * 8;
      qah[mf][ks] = ld_bf8(qlh + off);
      qal[mf][ks] = ld_bf8(qll + off);
    }
  bf16x8 onesf;
#pragma unroll
  for (int j = 0; j < 8; ++j) onesf[j] = (__bf16)1.0f;

  f32x4 kvacc[4][4] = {};
  f32x4 oneacc[4] = {};
  f32x4 ssum[4] = {};

  for (int sub = 0; sub < 4; ++sub) {
    int n0 = ch * 1024 + w * 256 + sub * 64;
    f32x4 sacc[4][4] = {};
#pragma unroll
    for (int ks = 0; ks < 2; ++ks) {
#pragma unroll
      for (int nf = 0; nf < 4; ++nf) {
        bf16x8 kb = ld_bf8(k4 + ((size_t)bh * N_ + n0 + nf * 16 + lrow) * 64 + ks * 32 + lgrp * 8);
#pragma unroll
        for (int mf = 0; mf < 4; ++mf) {
          sacc[mf][nf] = __builtin_amdgcn_mfma_f32_16x16x32_bf16(qah[mf][ks], kb, sacc[mf][nf], 0, 0, 0);
          sacc[mf][nf] = __builtin_amdgcn_mfma_f32_16x16x32_bf16(qal[mf][ks], kb, sacc[mf][nf], 0, 0, 0);
        }
      }
    }
#pragma unroll
    for (int mf = 0; mf < 4; ++mf) {
#pragma unroll
      for (int nf = 0; nf < 4; ++nf) {
#pragma unroll
        for (int r = 0; r < 4; ++r) {
          float pd = expf(sacc[mf][nf][r]) - 1.0f;
          ssum[mf][r] += pd;
          myP[(mf * 16 + lgrp * 4 + r) * 72 + nf * 16 + lrow] = f2bf(pd);
        }
      }
    }
#pragma unroll
    for (int ks = 0; ks < 2; ++ks) {
      bf16x8 pa[4];
#pragma unroll
      for (int mf = 0; mf < 4; ++mf)
        pa[mf] = ld_bf8(myP + (mf * 16 + lrow) * 72 + ks * 32 + lgrp * 8);
#pragma unroll
      for (int nf = 0; nf < 4; ++nf) {
        bf16x8 vb = ld_bf8(vt + ((size_t)bh * 64 + nf * 16 + lrow) * N_ + n0 + ks * 32 + lgrp * 8);
#pragma unroll
        for (int mf = 0; mf < 4; ++mf)
          kvacc[mf][nf] = __builtin_amdgcn_mfma_f32_16x16x32_bf16(pa[mf], vb, kvacc[mf][nf], 0, 0, 0);
        oneacc[nf] = __builtin_amdgcn_mfma_f32_16x16x32_bf16(onesf, vb, oneacc[nf], 0, 0, 0);
      }
    }
  }
#pragma unroll
  for (int mf = 0; mf < 4; ++mf)
#pragma unroll
    for (int m = 1; m < 16; m <<= 1)
#pragma unroll
      for (int r = 0; r < 4; ++r) ssum[mf][r] += __shfl_xor(ssum[mf][r], m);

  size_t pb = (((size_t)bh * NPART_ + part) * 64) * 64;
#pragma unroll
  for (int mf = 0; mf < 4; ++mf)
#pragma unroll
    for (int nf = 0; nf < 4; ++nf)
#pragma unroll
      for (int r = 0; r < 4; ++r)
        pacc[pb + (size_t)(mf * 16 + lgrp * 4 + r) * 64 + nf * 16 + lrow] = kvacc[mf][nf][r];
  if (lrow == 0) {
#pragma unroll
    for (int mf = 0; mf < 4; ++mf)
#pragma unroll
      for (int r = 0; r < 4; ++r)
        ps[((size_t)bh * NPART_ + part) * 64 + mf * 16 + lgrp * 4 + r] = ssum[mf][r];
  }
  if (lgrp == 0) {
#pragma unroll
    for (int nf = 0; nf < 4; ++nf)
      pacc0[((size_t)bh * NPART_ + part) * 64 + nf * 16 + lrow] = oneacc[nf][0];
  }
}

// Fused 2 (512 threads): blocks 0..15 = SVD phase 2 (8-wave);
// blocks 16..143 = ker3kv, two chunks per block (barrier-free body).
__global__ __launch_bounds__(512, 1) void fused2_kernel(
    const unsigned short* __restrict__ qlh,
    const unsigned short* __restrict__ qll,
    const unsigned short* __restrict__ k4,
    const unsigned short* __restrict__ vt,
    float* __restrict__ pacc, float* __restrict__ pacc0, float* __restrict__ ps,
    const float* __restrict__ asave, const float* __restrict__ vsave,
    float* __restrict__ pinv) {
  __shared__ __align__(16) char smem[73728];
  int tid = threadIdx.x;
  int blk = blockIdx.x;
  if (blk < 16) { svd_phase2(asave, vsave, pinv, blk, smem, tid); return; }
  int g = blk - 16;                // 0..127
  int bh = g >> 3, cpair = g & 7;
  int half = tid >> 8;
  int ltid = tid & 255;
  int ch = cpair * 2 + half;
  ker3kv_body(qlh, qll, k4, vt, pacc, pacc0, ps, bh, ch, smem + half * 36864, ltid);
}

// ---------------------------------------------------------------------------
// Fused combine+mmat (identical math/order to split kernels).
__global__ __launch_bounds__(256) void cm_kernel(const float* __restrict__ pacc,
                                                 const float* __restrict__ pacc0,
                                                 const float* __restrict__ ps,
                                                 const float* __restrict__ pinv,
                                                 unsigned short* __restrict__ mtbh,
                                                 unsigned short* __restrict__ mtbl,
                                                 float* __restrict__ msum) {
  int bh = blockIdx.x;
  int tid = threadIdx.x;
  __shared__ float kvs[64][68];
  __shared__ double pcsd[64];
  for (int g = 0; g < 4; ++g) {
    int lm = g * 16 + (tid >> 4);
    int d4 = (tid & 15) * 4;
    float s = 16384.f;
    for (int part = 0; part < NPART_; ++part) s += ps[((size_t)bh * NPART_ + part) * 64 + lm];
    float4 a = make_float4(0.f, 0.f, 0.f, 0.f);
    for (int part = 0; part < NPART_; ++part) {
      float4 c0 = *(const float4*)&pacc0[((size_t)bh * NPART_ + part) * 64 + d4];
      float4 v = *(const float4*)&pacc[(((size_t)bh * NPART_ + part) * 64 + lm) * 64 + d4];
      a.x += c0.x + v.x; a.y += c0.y + v.y; a.z += c0.z + v.z; a.w += c0.w + v.w;
    }
    float inv = 1.f / s;
    kvs[lm][d4 + 0] = a.x * inv; kvs[lm][d4 + 1] = a.y * inv;
    kvs[lm][d4 + 2] = a.z * inv; kvs[lm][d4 + 3] = a.w * inv;
  }
  if (tid < 64) {
    double s = 0.0;
    for (int l = 0; l < 64; ++l) s += (double)pinv[((size_t)bh * 64 + l) * 64 + tid];
    pcsd[tid] = s;
  }
  __syncthreads();
  int l = tid >> 2, t = tid & 3;
  double o[16] = {};
  for (int j = 0; j < 64; ++j) {
    double pv = (double)pinv[((size_t)bh * 64 + l) * 64 + j];
#pragma unroll
    for (int i = 0; i < 16; ++i) o[i] += pv * (double)kvs[j][t * 16 + i];
  }
#pragma unroll
  for (int i = 0; i < 16; ++i) {
    float f = (float)o[i];
    unsigned short hi = f2bf(f);
    float lo = f - bf2f(hi);
    int d = t * 16 + i;
    mtbh[((size_t)bh * 64 + d) * 64 + l] = hi;
    mtbl[((size_t)bh * 64 + d) * 64 + l] = f2bf(lo);
  }
  if (tid < 64) {
    double m = 0.0;
    for (int j = 0; j < 64; ++j) m += pcsd[j] * (double)kvs[j][tid];
    msum[(size_t)bh * 64 + tid] = (float)(m * (1.0 / 64.0));
  }
}

// ---------------------------------------------------------------------------
__global__ __launch_bounds__(256, 1) void ker1out_mfma_kernel(
    const unsigned short* __restrict__ q4,
    const unsigned short* __restrict__ klb,
    const unsigned short* __restrict__ mtbh,
    const unsigned short* __restrict__ mtbl,
    const float* __restrict__ msum,
    unsigned short* __restrict__ outh) {
  int bh = blockIdx.y, tile = blockIdx.x;
  int b = bh >> 3, h = bh & 7;
  int tid = threadIdx.x, w = tid >> 6, lane = tid & 63;
  int lrow = lane & 15, lgrp = lane >> 4;
  int tok0 = tile * 256 + w * 64;
  __shared__ __align__(16) unsigned short Pl[4][64 * 72];
  unsigned short* myP = &Pl[w][0];

  f32x4 sacc[4][4] = {};
#pragma unroll
  for (int ks = 0; ks < 2; ++ks) {
    bf16x8 kb[4];
#pragma unroll
    for (int nf = 0; nf < 4; ++nf)
      kb[nf] = ld_bf8(klb + ((size_t)bh * 64 + nf * 16 + lrow) * 64 + ks * 32 + lgrp * 8);
#pragma unroll
    for (int mf = 0; mf < 4; ++mf) {
      bf16x8 qa = ld_bf8(q4 + ((size_t)bh * N_ + tok0 + mf * 16 + lrow) * 64 + ks * 32 + lgrp * 8);
#pragma unroll
      for (int nf = 0; nf < 4; ++nf)
        sacc[mf][nf] = __builtin_amdgcn_mfma_f32_16x16x32_bf16(qa, kb[nf], sacc[mf][nf], 0, 0, 0);
    }
  }
  f32x4 ssum[4] = {};
#pragma unroll
  for (int mf = 0; mf < 4; ++mf)
#pragma unroll
    for (int nf = 0; nf < 4; ++nf)
#pragma unroll
      for (int r = 0; r < 4; ++r) {
        sacc[mf][nf][r] = expf(sacc[mf][nf][r]);
        ssum[mf][r] += sacc[mf][nf][r];
      }
#pragma unroll
  for (int mf = 0; mf < 4; ++mf)
#pragma unroll
    for (int m = 1; m < 16; m <<= 1)
#pragma unroll
      for (int r = 0; r < 4; ++r) ssum[mf][r] += __shfl_xor(ssum[mf][r], m);
#pragma unroll
  for (int mf = 0; mf < 4; ++mf) {
    f32x4 inv;
#pragma unroll
    for (int r = 0; r < 4; ++r) inv[r] = 1.f / ssum[mf][r];
#pragma unroll
    for (int nf = 0; nf < 4; ++nf)
#pragma unroll
      for (int r = 0; r < 4; ++r) {
        float pdev = fmaf(sacc[mf][nf][r], inv[r], -0.015625f);
        myP[(mf * 16 + lgrp * 4 + r) * 72 + nf * 16 + lrow] = f2bf(pdev);
      }
  }

  f32x4 oacc[4][4] = {};
#pragma unroll
  for (int ks = 0; ks < 2; ++ks) {
    bf16x8 pa[4];
#pragma unroll
    for (int mf = 0; mf < 4; ++mf)
      pa[mf] = ld_bf8(myP + (mf * 16 + lrow) * 72 + ks * 32 + lgrp * 8);
#pragma unroll
    for (int nf = 0; nf < 4; ++nf) {
      bf16x8 mh = ld_bf8(mtbh + ((size_t)bh * 64 + nf * 16 + lrow) * 64 + ks * 32 + lgrp * 8);
      bf16x8 ml = ld_bf8(mtbl + ((size_t)bh * 64 + nf * 16 + lrow) * 64 + ks * 32 + lgrp * 8);
#pragma unroll
      for (int mf = 0; mf < 4; ++mf) {
        oacc[mf][nf] = __builtin_amdgcn_mfma_f32_16x16x32_bf16(pa[mf], mh, oacc[mf][nf], 0, 0, 0);
        oacc[mf][nf] = __builtin_amdgcn_mfma_f32_16x16x32_bf16(pa[mf], ml, oacc[mf][nf], 0, 0, 0);
      }
    }
  }
#pragma unroll
  for (int nf = 0; nf < 4; ++nf) {
    float ms = msum[(size_t)bh * 64 + nf * 16 + lrow];
#pragma unroll
    for (int mf = 0; mf < 4; ++mf)
#pragma unroll
      for (int r = 0; r < 4; ++r) {
        int tok = tok0 + mf * 16 + lgrp * 4 + r;
        int d = nf * 16 + lrow;
        outh[((size_t)b * N_ + tok) * C_ + h * HD_ + d] = f2bf(oacc[mf][nf][r] + ms);
      }
  }
}

// ---------------------------------------------------------------------------
// Final projection (serial tail): outh(bf16) @ wob^T(bf16) + bo -> f32 out.
__global__ __launch_bounds__(256) void oproj_kernel(const unsigned short* __restrict__ outh,
                                                    const unsigned short* __restrict__ wob,
                                                    const float* __restrict__ bo,
                                                    float* __restrict__ out) {
  __shared__ __align__(16) unsigned short Xs[128 * 64];
  __shared__ __align__(16) unsigned short Wl[128 * 64];
  dma_gemm_body(outh, wob, bo, out, 1.0f, 0, blockIdx.x * 128, blockIdx.y * 128,
                Xs, Wl, threadIdx.x);
}

// ---------------------------------------------------------------------------
extern "C" void kernel_launch(void* const* d_in, const int* in_sizes, int n_in,
                              void* d_out, int out_size, void* d_ws, size_t ws_size,
                              hipStream_t stream) {
  const float* x  = (const float*)d_in[0];
  const float* wq = (const float*)d_in[1];
  const float* bq = (const float*)d_in[2];
  const float* wk = (const float*)d_in[3];
  const float* bk = (const float*)d_in[4];
  const float* wv = (const float*)d_in[5];
  const float* bv = (const float*)d_in[6];
  const float* wo = (const float*)d_in[7];
  const float* bo = (const float*)d_in[8];
  float* out = (float*)d_out;

  char* base = (char*)d_ws;
  const size_t QKV = (size_t)BH_ * N_ * HD_;
  unsigned short* q4 = (unsigned short*)base;                 // 32MB
  unsigned short* k4 = (unsigned short*)(base + QKV * 2);     // 32MB
  unsigned short* vt = (unsigned short*)(base + QKV * 4);     // 32MB
  unsigned short* outh = (unsigned short*)(base + QKV * 2);   // alias k4 (dead after ker3kv)
  char* sp = base + QKV * 6;
  float* pacc  = (float*)sp; sp += (size_t)BH_ * NPART_ * 64 * 64 * 4;  // 16.78MB
  float* pacc0 = (float*)sp; sp += (size_t)BH_ * NPART_ * 64 * 4;
  float* ps    = (float*)sp; sp += (size_t)BH_ * NPART_ * 64 * 4;
  float* xbar  = (float*)sp; sp += (size_t)B_ * LM_ * C_ * 4;
  float* qland = (float*)sp; sp += (size_t)BH_ * LM_ * HD_ * 4;
  float* kland = (float*)sp; sp += (size_t)BH_ * LM_ * HD_ * 4;
  unsigned short* qlbh = (unsigned short*)sp; sp += (size_t)BH_ * LM_ * HD_ * 2;
  unsigned short* qlbl = (unsigned short*)sp; sp += (size_t)BH_ * LM_ * HD_ * 2;
  unsigned short* klb  = (unsigned short*)sp; sp += (size_t)BH_ * LM_ * HD_ * 2;
  float* pinv  = (float*)sp; sp += (size_t)BH_ * LM_ * LM_ * 4;
  unsigned short* mtbh = (unsigned short*)sp; sp += (size_t)BH_ * LM_ * HD_ * 2;
  unsigned short* mtbl = (unsigned short*)sp; sp += (size_t)BH_ * LM_ * HD_ * 2;
  float* msum  = (float*)sp; sp += (size_t)BH_ * HD_ * 4;
  float* asave = (float*)sp; sp += (size_t)BH_ * LM_ * LM_ * 4;   // 256KB
  float* vsave = (float*)sp; sp += (size_t)BH_ * LM_ * LM_ * 4;   // 256KB
  unsigned short* wob = (unsigned short*)sp; sp += (size_t)C_ * C_ * 2;  // 512KB
  unsigned short* wqb = (unsigned short*)sp; sp += (size_t)C_ * C_ * 2;  // 512KB
  unsigned short* wkb = (unsigned short*)sp; sp += (size_t)C_ * C_ * 2;  // 512KB
  unsigned short* wvb = (unsigned short*)sp; sp += (size_t)C_ * C_ * 2;  // 512KB

  // xb (bf16 x, 32MB) lives in d_out's first half (dead until oproj).
  unsigned short* xb = (unsigned short*)d_out;

  const int W8 = (C_ * C_) / 8;

  dim3 gc(W8 / 256, 4);
  cvt_w4_kernel<<<gc, 256, 0, stream>>>(wq, wk, wv, wo, wqb, wkb, wvb, wob);

  seg_mean_kernel<<<B_ * LM_, 512, 0, stream>>>(x, xbar, xb);
  dim3 gl(4, 8);
  land_gemm_kernel<<<gl, 256, 0, stream>>>(xbar, wq, bq, wk, bk,
                                           qland, kland, qlbh, qlbl, klb);

  // fused 1: SVD phase 1 (8-wave, 3 sweeps) + DMA projections (BK=64)
  fused1_kernel<<<16 + 3 * 512, 512, 0, stream>>>(
      xb, wqb, bq, wkb, bk, wvb, bv, q4, k4, vt, qland, kland, asave, vsave);

  // fused 2: SVD phase 2 (8-wave, 2 sweeps + pinv) + ker3kv (2 chunks/blk)
  fused2_kernel<<<16 + BH_ * 8, 512, 0, stream>>>(
      qlbh, qlbl, k4, vt, pacc, pacc0, ps, asave, vsave, pinv);

  // combine + M (fused)
  cm_kernel<<<BH_, 256, 0, stream>>>(pacc, pacc0, ps, pinv, mtbh, mtbl, msum);

  dim3 g9(N_ / 256, BH_);
  ker1out_mfma_kernel<<<g9, 256, 0, stream>>>(q4, klb, mtbh, mtbl, msum, outh);

  dim3 g10(B_ * N_ / 128, C_ / 128);
  oproj_kernel<<<g10, 256, 0, stream>>>(outh, wob, bo, out);
}